// Round 1
// baseline (420.997 us; speedup 1.0000x reference)
//
#include <hip/hip_runtime.h>
#include <hip/hip_fp16.h>

typedef _Float16 f16x8 __attribute__((ext_vector_type(8)));
typedef float f32x4 __attribute__((ext_vector_type(4)));

#define NB 32
#define NK 64
#define ND 4
#define NH 512
#define NKP 544   // node-input K (520) padded to 17*32

// ---------------------------------------------------------------- prep ----

__global__ void prep_obs_kernel(const float* __restrict__ obs,
                                const float* __restrict__ state,
                                float* __restrict__ o,
                                float* __restrict__ maskp,
                                float* __restrict__ cntp,
                                _Float16* __restrict__ nodein) {
  const int b = blockIdx.x;
  const int j = threadIdx.x;  // 64
  float o0 = obs[(b*4 + 0)*64 + j];
  float o1 = obs[(b*4 + 1)*64 + j];
  float o2 = obs[(b*4 + 2)*64 + j];
  float o3 = obs[(b*4 + 3)*64 + j];
  size_t bi = (size_t)b*64 + j;
  float* orow = o + bi*4;
  orow[0] = o0; orow[1] = o1; orow[2] = o2; orow[3] = o3;
  float s = fabsf(o0) + fabsf(o1) + fabsf(o2) + fabsf(o3);
  float m = (s != 0.0f) ? 1.0f : 0.0f;
  maskp[bi] = m;
  float c = m;
  #pragma unroll
  for (int off = 1; off < 64; off <<= 1) c += __shfl_xor(c, off);
  if (j == 0) cntp[b] = fmaxf(c, 1e-6f);
  _Float16* nrow = nodein + bi*NKP;
  nrow[0] = (_Float16)o0; nrow[1] = (_Float16)o1;
  nrow[2] = (_Float16)o2; nrow[3] = (_Float16)o3;
  nrow[516] = (_Float16)state[b*4 + 0];
  nrow[517] = (_Float16)state[b*4 + 1];
  nrow[518] = (_Float16)state[b*4 + 2];
  nrow[519] = (_Float16)state[b*4 + 3];
  for (int k2 = 520; k2 < 544; ++k2) nrow[k2] = (_Float16)0.0f;
}

__global__ void prep_ubv_kernel(const float* __restrict__ o,
                                const float* __restrict__ e1w,
                                const float* __restrict__ e1b,
                                float* __restrict__ ubp,
                                float* __restrict__ vp) {
  const int bi = blockIdx.x;     // 2048
  const int c = threadIdx.x;     // 512
  const float* orow = o + (size_t)bi*4;
  float o0 = orow[0], o1 = orow[1], o2 = orow[2], o3 = orow[3];
  const float* wr = e1w + c*8;
  ubp[(size_t)bi*NH + c] = wr[0]*o0 + wr[1]*o1 + wr[2]*o2 + wr[3]*o3 + e1b[c];
  vp [(size_t)bi*NH + c] = wr[4]*o0 + wr[5]*o1 + wr[6]*o2 + wr[7]*o3;
}

__global__ void prep_w16_kernel(const float* __restrict__ e2w,
                                const float* __restrict__ e3w,
                                const float* __restrict__ n2w,
                                const float* __restrict__ n1w,
                                _Float16* __restrict__ w2h,
                                _Float16* __restrict__ w3h,
                                _Float16* __restrict__ n2wh,
                                _Float16* __restrict__ n1wh) {
  int idx = blockIdx.x * blockDim.x + threadIdx.x;
  const int A = 512*512, Bc = 512*512, C = 256*512, Dn = 512*544;
  if (idx < A) {
    w2h[idx] = (_Float16)e2w[idx];
  } else if (idx < A + Bc) {
    int q = idx - A; w3h[q] = (_Float16)e3w[q];
  } else if (idx < A + Bc + C) {
    int q = idx - A - Bc; n2wh[q] = (_Float16)n2w[q];
  } else if (idx < A + Bc + C + Dn) {
    int q = idx - A - Bc - C;
    int n = q / 544, k = q % 544;
    n1wh[q] = (k < 520) ? (_Float16)n1w[n*520 + k] : (_Float16)0.0f;
  }
}

__global__ void prep_stfeat_kernel(const float* __restrict__ state,
                                   const float* __restrict__ lw,
                                   const float* __restrict__ lb,
                                   float* __restrict__ xfeat) {
  const int b = blockIdx.x, c = threadIdx.x;  // 512
  const float* s = state + b*4;
  const float* wr = lw + c*4;
  float hv = wr[0]*s[0] + wr[1]*s[1] + wr[2]*s[2] + wr[3]*s[3] + lb[c];
  xfeat[b*1024 + c] = fmaxf(hv, 0.0f);
}

// ---------------------------------------------------------------- edge ----

__device__ __forceinline__ void gemm_layer(const char* hb,
                                           const _Float16* __restrict__ wbase0,
                                           const float* __restrict__ biasp,
                                           int colbase, int lr, int lg,
                                           f32x4 acc[4][4]) {
  #pragma unroll
  for (int nt = 0; nt < 4; ++nt) {
    float bz = biasp[colbase + nt*16 + lr];
    #pragma unroll
    for (int mt = 0; mt < 4; ++mt) {
      acc[mt][nt][0] = bz; acc[mt][nt][1] = bz;
      acc[mt][nt][2] = bz; acc[mt][nt][3] = bz;
    }
  }
  const _Float16* wbase = wbase0 + ((size_t)(colbase + lr))*NH + lg*8;
  for (int kk = 0; kk < 16; ++kk) {
    f16x8 bf[4];
    #pragma unroll
    for (int nt = 0; nt < 4; ++nt)
      bf[nt] = *(const f16x8*)(wbase + nt*16*NH + kk*32);
    f16x8 af[4];
    #pragma unroll
    for (int mt = 0; mt < 4; ++mt) {
      int row = mt*16 + lr;
      af[mt] = *(const f16x8*)(hb + (((row*NH + kk*32 + lg*8)*2) ^ ((row & 7) << 4)));
    }
    #pragma unroll
    for (int mt = 0; mt < 4; ++mt)
      #pragma unroll
      for (int nt = 0; nt < 4; ++nt)
        acc[mt][nt] = __builtin_amdgcn_mfma_f32_16x16x32_f16(af[mt], bf[nt], acc[mt][nt], 0, 0, 0);
  }
}

__global__ __launch_bounds__(512, 2) void edge_kernel(
    const float* __restrict__ ubp, const float* __restrict__ vp,
    const float* __restrict__ maskp, const float* __restrict__ cntp,
    const _Float16* __restrict__ w2h, const _Float16* __restrict__ w3h,
    const float* __restrict__ e2b, const float* __restrict__ e3b,
    const float* __restrict__ lng, const float* __restrict__ lnb,
    _Float16* __restrict__ nodein) {
  __shared__ __align__(16) _Float16 hts[NK * NH];   // 64 KB; holds H1 then H2
  __shared__ __align__(16) float u_s[NH];
  __shared__ float em_s[NK];
  __shared__ float red_s[16];
  __shared__ float stat_s[2];
  __shared__ float agg_s[NH];

  const int t = threadIdx.x;
  const int bi = blockIdx.x;
  const int b = bi >> 6;
  const int iq = bi & 63;
  char* hb = (char*)hts;

  u_s[t] = ubp[(size_t)bi*NH + t];
  if (t < NK) em_s[t] = maskp[(size_t)b*NK + t];
  __syncthreads();

  // H1[j][c] = relu(u[c] + v[j][c]) -> LDS f16, XOR-swizzled rows
  {
    const int j = t >> 3;
    const int c0 = (t & 7) * 64;
    const float* vrow = vp + ((size_t)b*NK + j)*NH;
    #pragma unroll
    for (int cc = 0; cc < 64; cc += 8) {
      int c = c0 + cc;
      float4 v0 = *(const float4*)(vrow + c);
      float4 v1 = *(const float4*)(vrow + c + 4);
      float4 u0 = *(const float4*)(u_s + c);
      float4 u1 = *(const float4*)(u_s + c + 4);
      f16x8 hv;
      hv[0] = (_Float16)fmaxf(u0.x + v0.x, 0.0f);
      hv[1] = (_Float16)fmaxf(u0.y + v0.y, 0.0f);
      hv[2] = (_Float16)fmaxf(u0.z + v0.z, 0.0f);
      hv[3] = (_Float16)fmaxf(u0.w + v0.w, 0.0f);
      hv[4] = (_Float16)fmaxf(u1.x + v1.x, 0.0f);
      hv[5] = (_Float16)fmaxf(u1.y + v1.y, 0.0f);
      hv[6] = (_Float16)fmaxf(u1.z + v1.z, 0.0f);
      hv[7] = (_Float16)fmaxf(u1.w + v1.w, 0.0f);
      *(f16x8*)(hb + (((j*NH + c)*2) ^ ((j & 7) << 4))) = hv;
    }
  }
  __syncthreads();

  const int w = t >> 6;
  const int l = t & 63;
  const int lr = l & 15;
  const int lg = l >> 4;
  const int colbase = w * 64;

  f32x4 acc[4][4];

  // layer 2: acc = H1 @ W2^T + b2
  gemm_layer(hb, w2h, e2b, colbase, lr, lg, acc);
  __syncthreads();  // all waves finished reading H1
  // H2 = relu(acc) overwrites H1 buffer (same swizzled layout)
  #pragma unroll
  for (int mt = 0; mt < 4; ++mt)
    #pragma unroll
    for (int nt = 0; nt < 4; ++nt)
      #pragma unroll
      for (int r = 0; r < 4; ++r) {
        int row = mt*16 + lg*4 + r;
        int col = colbase + nt*16 + lr;
        *(_Float16*)(hb + (((row*NH + col)*2) ^ ((row & 7) << 4))) =
            (_Float16)fmaxf(acc[mt][nt][r], 0.0f);
      }
  __syncthreads();

  // layer 3: acc = H2 @ W3^T + b3
  gemm_layer(hb, w3h, e3b, colbase, lr, lg, acc);

  // masked sum over j, then /valid_counts
  float colsum[4] = {0.f, 0.f, 0.f, 0.f};
  #pragma unroll
  for (int mt = 0; mt < 4; ++mt) {
    float em0 = em_s[mt*16 + lg*4 + 0];
    float em1 = em_s[mt*16 + lg*4 + 1];
    float em2 = em_s[mt*16 + lg*4 + 2];
    float em3 = em_s[mt*16 + lg*4 + 3];
    #pragma unroll
    for (int nt = 0; nt < 4; ++nt) {
      colsum[nt] += em0 * fmaxf(acc[mt][nt][0], 0.f)
                  + em1 * fmaxf(acc[mt][nt][1], 0.f)
                  + em2 * fmaxf(acc[mt][nt][2], 0.f)
                  + em3 * fmaxf(acc[mt][nt][3], 0.f);
    }
  }
  #pragma unroll
  for (int nt = 0; nt < 4; ++nt) {
    colsum[nt] += __shfl_xor(colsum[nt], 16);
    colsum[nt] += __shfl_xor(colsum[nt], 32);
  }
  float scale = em_s[iq] / cntp[b];  // cnt already clipped >=1e-6
  if (lg == 0) {
    #pragma unroll
    for (int nt = 0; nt < 4; ++nt)
      agg_s[colbase + nt*16 + lr] = colsum[nt] * scale;
  }
  __syncthreads();

  // LayerNorm over 512 channels
  float a = agg_s[t];
  float s1 = a, s2 = a * a;
  #pragma unroll
  for (int off = 1; off < 64; off <<= 1) {
    s1 += __shfl_xor(s1, off);
    s2 += __shfl_xor(s2, off);
  }
  if (l == 0) { red_s[w] = s1; red_s[8 + w] = s2; }
  __syncthreads();
  if (t == 0) {
    float S1 = 0.f, S2 = 0.f;
    for (int q = 0; q < 8; ++q) { S1 += red_s[q]; S2 += red_s[8 + q]; }
    float mean = S1 / 512.0f;
    float var = S2 / 512.0f - mean * mean;
    stat_s[0] = mean;
    stat_s[1] = rsqrtf(var + 1e-5f);
  }
  __syncthreads();
  float nrm = (a - stat_s[0]) * stat_s[1] * lng[t] + lnb[t];
  nodein[(size_t)bi*NKP + 4 + t] = (_Float16)nrm;
}

// ---------------------------------------------------------------- node ----

template <int RELU16>
__global__ __launch_bounds__(256) void node_gemm(
    const _Float16* __restrict__ A, const _Float16* __restrict__ Bw,
    const float* __restrict__ bias, void* __restrict__ outp,
    int Ka, int ldo) {
  const int t = threadIdx.x;
  const int w = t >> 6, l = t & 63, lr = l & 15, lg = l >> 4;
  const int m0 = blockIdx.x * 64;
  const int col = blockIdx.y * 64 + w*16 + lr;
  f32x4 acc[4];
  float bz = bias[col];
  #pragma unroll
  for (int mt = 0; mt < 4; ++mt) {
    acc[mt][0] = bz; acc[mt][1] = bz; acc[mt][2] = bz; acc[mt][3] = bz;
  }
  const _Float16* bptr = Bw + (size_t)col*Ka + lg*8;
  const _Float16* aptr = A + (size_t)(m0 + lr)*Ka + lg*8;
  const int nkk = Ka >> 5;
  for (int kk = 0; kk < nkk; ++kk) {
    f16x8 bf = *(const f16x8*)(bptr + kk*32);
    #pragma unroll
    for (int mt = 0; mt < 4; ++mt) {
      f16x8 af = *(const f16x8*)(aptr + ((size_t)mt*16)*Ka + kk*32);
      acc[mt] = __builtin_amdgcn_mfma_f32_16x16x32_f16(af, bf, acc[mt], 0, 0, 0);
    }
  }
  #pragma unroll
  for (int mt = 0; mt < 4; ++mt)
    #pragma unroll
    for (int r = 0; r < 4; ++r) {
      int row = m0 + mt*16 + lg*4 + r;
      float vv = acc[mt][r];
      if (RELU16)
        ((_Float16*)outp)[(size_t)row*ldo + col] = (_Float16)fmaxf(vv, 0.f);
      else
        ((float*)outp)[(size_t)row*ldo + col] = vv;
    }
}

// ----------------------------------------------------------- pool/heads ----

__global__ __launch_bounds__(256) void pool_kernel(
    const float* __restrict__ nodeout, const float* __restrict__ maskp,
    const float* __restrict__ cntp, float* __restrict__ xfeat) {
  const int b = blockIdx.x;
  const int c = threadIdx.x;  // 256
  float sum = 0.f, mx = -1e9f;
  for (int i = 0; i < 64; ++i) {
    float m = maskp[b*64 + i];
    float v = nodeout[((size_t)(b*64 + i))*256 + c];
    sum += m * v;
    mx = fmaxf(mx, (m != 0.f) ? v : -1e9f);
  }
  xfeat[b*1024 + 512 + c] = sum / cntp[b];
  xfeat[b*1024 + 768 + c] = mx;
}

__global__ __launch_bounds__(512) void heads_kernel(
    const float* __restrict__ xfeat,
    const float* __restrict__ mu1w, const float* __restrict__ mu1b,
    const float* __restrict__ mu2w, const float* __restrict__ mu2b,
    const float* __restrict__ mu3w, const float* __restrict__ mu3b,
    const float* __restrict__ s1w, const float* __restrict__ s1b,
    const float* __restrict__ s2w, const float* __restrict__ s2b,
    const float* __restrict__ s3w, const float* __restrict__ s3b,
    float* __restrict__ outp) {
  __shared__ __align__(16) float xs[1024];
  __shared__ __align__(16) float h1[512];
  __shared__ __align__(16) float h2[256];
  const int b = blockIdx.x;
  const int t = threadIdx.x;
  xs[t] = xfeat[b*1024 + t];
  xs[t + 512] = xfeat[b*1024 + 512 + t];
  __syncthreads();
  {
    const int oo = t & 255;
    const bool sp = t >= 256;
    const float* wr = (sp ? s1w : mu1w) + (size_t)oo*1024;
    float a = (sp ? s1b : mu1b)[oo];
    for (int k = 0; k < 1024; k += 4) {
      float4 ww = *(const float4*)(wr + k);
      float4 xx = *(const float4*)(xs + k);
      a += ww.x*xx.x + ww.y*xx.y + ww.z*xx.z + ww.w*xx.w;
    }
    h1[(sp ? 256 : 0) + oo] = fmaxf(a, 0.f);
  }
  __syncthreads();
  if (t < 256) {
    const int oo = t & 127;
    const bool sp = t >= 128;
    const float* wr = (sp ? s2w : mu2w) + (size_t)oo*256;
    const float* hbp = h1 + (sp ? 256 : 0);
    float a = (sp ? s2b : mu2b)[oo];
    for (int k = 0; k < 256; k += 4) {
      float4 ww = *(const float4*)(wr + k);
      float4 hh = *(const float4*)(hbp + k);
      a += ww.x*hh.x + ww.y*hh.y + ww.z*hh.z + ww.w*hh.w;
    }
    h2[(sp ? 128 : 0) + oo] = fmaxf(a, 0.f);
  }
  __syncthreads();
  if (t < 4) {
    const int oo = t & 1;
    const bool sp = t >= 2;
    const float* wr = (sp ? s3w : mu3w) + oo*128;
    const float* hbp = h2 + (sp ? 128 : 0);
    float a = (sp ? s3b : mu3b)[oo];
    for (int k = 0; k < 128; ++k) a += wr[k] * hbp[k];
    if (!sp) {
      outp[b*2 + oo] = a;
    } else {
      float spv = (a > 0.f) ? (a + log1pf(expf(-a))) : log1pf(expf(a));
      float sd = fminf(fmaxf(spv + 0.001f, 0.1f), 2.0f);
      outp[64 + b*2 + oo] = sd;
    }
  }
}

// --------------------------------------------------------------- launch ----

extern "C" void kernel_launch(void* const* d_in, const int* in_sizes, int n_in,
                              void* d_out, int out_size, void* d_ws, size_t ws_size,
                              hipStream_t stream) {
  const float* state  = (const float*)d_in[0];
  const float* obs    = (const float*)d_in[1];
  const float* layerw = (const float*)d_in[2];
  const float* layerb = (const float*)d_in[3];
  const float* e1w    = (const float*)d_in[4];
  const float* e1b    = (const float*)d_in[5];
  const float* e2w    = (const float*)d_in[6];
  const float* e2b    = (const float*)d_in[7];
  const float* e3w    = (const float*)d_in[8];
  const float* e3b    = (const float*)d_in[9];
  const float* lng    = (const float*)d_in[10];
  const float* lnb    = (const float*)d_in[11];
  const float* n1w    = (const float*)d_in[12];
  const float* n1b    = (const float*)d_in[13];
  const float* n2w    = (const float*)d_in[14];
  const float* n2b    = (const float*)d_in[15];
  const float* mu1w   = (const float*)d_in[16];
  const float* mu1b   = (const float*)d_in[17];
  const float* mu2w   = (const float*)d_in[18];
  const float* mu2b   = (const float*)d_in[19];
  const float* mu3w   = (const float*)d_in[20];
  const float* mu3b   = (const float*)d_in[21];
  const float* s1w    = (const float*)d_in[22];
  const float* s1b    = (const float*)d_in[23];
  const float* s2w    = (const float*)d_in[24];
  const float* s2b    = (const float*)d_in[25];
  const float* s3w    = (const float*)d_in[26];
  const float* s3b    = (const float*)d_in[27];
  float* outp = (float*)d_out;

  char* p = (char*)d_ws;
  auto alloc = [&](size_t bytes) {
    char* r = p;
    p += (bytes + 255) & ~(size_t)255;
    return r;
  };
  float*    o       = (float*)alloc((size_t)2048*4*4);
  float*    maskp   = (float*)alloc((size_t)2048*4);
  float*    cntp    = (float*)alloc((size_t)32*4);
  float*    ubp     = (float*)alloc((size_t)2048*512*4);
  float*    vp      = (float*)alloc((size_t)2048*512*4);
  _Float16* w2h     = (_Float16*)alloc((size_t)512*512*2);
  _Float16* w3h     = (_Float16*)alloc((size_t)512*512*2);
  _Float16* nodein  = (_Float16*)alloc((size_t)2048*544*2);
  _Float16* n1wh    = (_Float16*)alloc((size_t)512*544*2);
  _Float16* n2wh    = (_Float16*)alloc((size_t)256*512*2);
  _Float16* nodeh   = (_Float16*)alloc((size_t)2048*512*2);
  float*    nodeout = (float*)alloc((size_t)2048*256*4);
  float*    xfeat   = (float*)alloc((size_t)32*1024*4);

  prep_obs_kernel<<<32, 64, 0, stream>>>(obs, state, o, maskp, cntp, nodein);
  prep_ubv_kernel<<<2048, 512, 0, stream>>>(o, e1w, e1b, ubp, vp);
  prep_w16_kernel<<<3648, 256, 0, stream>>>(e2w, e3w, n2w, n1w, w2h, w3h, n2wh, n1wh);
  prep_stfeat_kernel<<<32, 512, 0, stream>>>(state, layerw, layerb, xfeat);
  edge_kernel<<<2048, 512, 0, stream>>>(ubp, vp, maskp, cntp, w2h, w3h,
                                        e2b, e3b, lng, lnb, nodein);
  node_gemm<1><<<dim3(32, 8), 256, 0, stream>>>(nodein, n1wh, n1b, (void*)nodeh, 544, 512);
  node_gemm<0><<<dim3(32, 4), 256, 0, stream>>>(nodeh, n2wh, n2b, (void*)nodeout, 512, 256);
  pool_kernel<<<32, 256, 0, stream>>>(nodeout, maskp, cntp, xfeat);
  heads_kernel<<<32, 512, 0, stream>>>(xfeat, mu1w, mu1b, mu2w, mu2b, mu3w, mu3b,
                                       s1w, s1b, s2w, s2b, s3w, s3b, outp);
}

// Round 2
// 343.392 us; speedup vs baseline: 1.2260x; 1.2260x over previous
//
#include <hip/hip_runtime.h>
#include <hip/hip_fp16.h>

typedef _Float16 f16x8 __attribute__((ext_vector_type(8)));
typedef _Float16 f16x4 __attribute__((ext_vector_type(4)));
typedef float f32x4 __attribute__((ext_vector_type(4)));

#define NB 32
#define NK 64
#define ND 4
#define NH 512
#define NKP 544   // node-input K (520) padded to 17*32
#define RTOT 131072

// ---------------------------------------------------------------- prep ----

__global__ void prep_obs_kernel(const float* __restrict__ obs,
                                const float* __restrict__ state,
                                float* __restrict__ o,
                                float* __restrict__ maskp,
                                float* __restrict__ cntp,
                                _Float16* __restrict__ nodein) {
  const int b = blockIdx.x;
  const int j = threadIdx.x;  // 64
  float o0 = obs[(b*4 + 0)*64 + j];
  float o1 = obs[(b*4 + 1)*64 + j];
  float o2 = obs[(b*4 + 2)*64 + j];
  float o3 = obs[(b*4 + 3)*64 + j];
  size_t bi = (size_t)b*64 + j;
  float* orow = o + bi*4;
  orow[0] = o0; orow[1] = o1; orow[2] = o2; orow[3] = o3;
  float s = fabsf(o0) + fabsf(o1) + fabsf(o2) + fabsf(o3);
  float m = (s != 0.0f) ? 1.0f : 0.0f;
  maskp[bi] = m;
  float c = m;
  #pragma unroll
  for (int off = 1; off < 64; off <<= 1) c += __shfl_xor(c, off);
  if (j == 0) cntp[b] = fmaxf(c, 1e-6f);
  _Float16* nrow = nodein + bi*NKP;
  nrow[0] = (_Float16)o0; nrow[1] = (_Float16)o1;
  nrow[2] = (_Float16)o2; nrow[3] = (_Float16)o3;
  nrow[516] = (_Float16)state[b*4 + 0];
  nrow[517] = (_Float16)state[b*4 + 1];
  nrow[518] = (_Float16)state[b*4 + 2];
  nrow[519] = (_Float16)state[b*4 + 3];
  for (int k2 = 520; k2 < 544; ++k2) nrow[k2] = (_Float16)0.0f;
}

// u16[bi][c] = W1[:, :4]·o_bi + b1  (f16);  v16[bi][c] = W1[:, 4:]·o_bi (f16)
__global__ void prep_uv16(const float* __restrict__ o,
                          const float* __restrict__ e1w,
                          const float* __restrict__ e1b,
                          _Float16* __restrict__ u16,
                          _Float16* __restrict__ v16) {
  const int bi = blockIdx.x;     // 2048
  const int c = threadIdx.x;     // 512
  const float* orow = o + (size_t)bi*4;
  float o0 = orow[0], o1 = orow[1], o2 = orow[2], o3 = orow[3];
  const float* wr = e1w + c*8;
  float u = wr[0]*o0 + wr[1]*o1 + wr[2]*o2 + wr[3]*o3 + e1b[c];
  float v = wr[4]*o0 + wr[5]*o1 + wr[6]*o2 + wr[7]*o3;
  u16[(size_t)bi*NH + c] = (_Float16)u;
  v16[(size_t)bi*NH + c] = (_Float16)v;
}

__global__ void prep_w16_kernel(const float* __restrict__ e2w,
                                const float* __restrict__ e3w,
                                const float* __restrict__ n2w,
                                const float* __restrict__ n1w,
                                _Float16* __restrict__ w2h,
                                _Float16* __restrict__ w3h,
                                _Float16* __restrict__ n2wh,
                                _Float16* __restrict__ n1wh) {
  int idx = blockIdx.x * blockDim.x + threadIdx.x;
  const int A = 512*512, Bc = 512*512, C = 256*512, Dn = 512*544;
  if (idx < A) {
    w2h[idx] = (_Float16)e2w[idx];
  } else if (idx < A + Bc) {
    int q = idx - A; w3h[q] = (_Float16)e3w[q];
  } else if (idx < A + Bc + C) {
    int q = idx - A - Bc; n2wh[q] = (_Float16)n2w[q];
  } else if (idx < A + Bc + C + Dn) {
    int q = idx - A - Bc - C;
    int n = q / 544, k = q % 544;
    n1wh[q] = (k < 520) ? (_Float16)n1w[n*520 + k] : (_Float16)0.0f;
  }
}

__global__ void prep_stfeat_kernel(const float* __restrict__ state,
                                   const float* __restrict__ lw,
                                   const float* __restrict__ lb,
                                   float* __restrict__ xfeat) {
  const int b = blockIdx.x, c = threadIdx.x;  // 512
  const float* s = state + b*4;
  const float* wr = lw + c*4;
  float hv = wr[0]*s[0] + wr[1]*s[1] + wr[2]*s[2] + wr[3]*s[3] + lb[c];
  xfeat[b*1024 + c] = fmaxf(hv, 0.0f);
}

// ------------------------------------------------------- edge (2 GEMMs) ----
// Geometry: WG tile 256 (rows) x 256 (cols), K=512 in 8 steps of 64.
// 512 threads = 8 waves, 2M x 4N, wave tile 128x64, acc[8][4] f32x4.
// LDS 128 KB: A0 @0, A1 @32768, B0 @65536, B1 @98304 (256x64 f16 each,
// XOR-swizzled: byte = (row*128 + kc*16) ^ ((row&7)<<4)).

__device__ __forceinline__ void stage_A_l2(char* abuf,
                                           const _Float16* __restrict__ u16,
                                           const _Float16* __restrict__ v16,
                                           int bi0, int b, int s, int t) {
  const int tr = t >> 3, kc = t & 7;
  const int kof = s*64 + kc*8;
  f16x8 vv = *(const f16x8*)(v16 + (size_t)(b*64 + tr)*NH + kof);
  #pragma unroll
  for (int p = 0; p < 4; ++p) {
    f16x8 uu = *(const f16x8*)(u16 + (size_t)(bi0 + p)*NH + kof);
    f16x8 hv;
    #pragma unroll
    for (int e = 0; e < 8; ++e) {
      _Float16 x = uu[e] + vv[e];
      hv[e] = x > (_Float16)0 ? x : (_Float16)0;
    }
    int rr = p*64 + tr;
    *(f16x8*)(abuf + ((rr*128 + kc*16) ^ ((rr & 7) << 4))) = hv;
  }
}

__device__ __forceinline__ void stage_W(char* bbuf,
                                        const _Float16* __restrict__ w,
                                        int colbase, int s, int t) {
  const int tr = t >> 3, kc = t & 7;
  const int kof = s*64 + kc*8;
  #pragma unroll
  for (int p = 0; p < 4; ++p) {
    int rr = p*64 + tr;
    f16x8 wv = *(const f16x8*)(w + (size_t)(colbase + rr)*NH + kof);
    *(f16x8*)(bbuf + ((rr*128 + kc*16) ^ ((rr & 7) << 4))) = wv;
  }
}

__device__ __forceinline__ void stage_H2(char* abuf,
                                         const _Float16* __restrict__ h2g,
                                         int mrel, int s, int t) {
  const int tr = t >> 3, kc = t & 7;
  const int kof = s*64 + kc*8;
  #pragma unroll
  for (int p = 0; p < 4; ++p) {
    int rr = p*64 + tr;
    f16x8 hv = *(const f16x8*)(h2g + (size_t)(mrel + rr)*NH + kof);
    *(f16x8*)(abuf + ((rr*128 + kc*16) ^ ((rr & 7) << 4))) = hv;
  }
}

__device__ __forceinline__ void compute_step(const char* abuf, const char* bbuf,
                                             int wm, int wn, int lr, int lg,
                                             f32x4 acc[8][4]) {
  #pragma unroll
  for (int kk = 0; kk < 2; ++kk) {
    const int sl = kk*4 + lg;
    f16x8 bf[4];
    #pragma unroll
    for (int nt = 0; nt < 4; ++nt) {
      int rb = wn*64 + nt*16 + lr;
      bf[nt] = *(const f16x8*)(bbuf + ((rb*128 + sl*16) ^ ((rb & 7) << 4)));
    }
    #pragma unroll
    for (int mt = 0; mt < 8; ++mt) {
      int ra = wm*128 + mt*16 + lr;
      f16x8 af = *(const f16x8*)(abuf + ((ra*128 + sl*16) ^ ((ra & 7) << 4)));
      #pragma unroll
      for (int nt = 0; nt < 4; ++nt)
        acc[mt][nt] = __builtin_amdgcn_mfma_f32_16x16x32_f16(af, bf[nt], acc[mt][nt], 0, 0, 0);
    }
  }
}

__global__ __launch_bounds__(512, 1) void edge_l2(
    const _Float16* __restrict__ u16, const _Float16* __restrict__ v16,
    const _Float16* __restrict__ w2h, const float* __restrict__ e2b,
    _Float16* __restrict__ h2g, int row0) {
  __shared__ __align__(16) char lds[131072];
  const int t = threadIdx.x;
  const int mrel = blockIdx.x * 256;
  const int rowbase = row0 + mrel;
  const int bi0 = rowbase >> 6;     // 4 consecutive bi, same b
  const int b = bi0 >> 6;
  const int colbase = blockIdx.y * 256;
  const int w = t >> 6, l = t & 63, lr = l & 15, lg = l >> 4;
  const int wm = w >> 2, wn = w & 3;

  f32x4 acc[8][4];
  #pragma unroll
  for (int nt = 0; nt < 4; ++nt) {
    float bz = e2b[colbase + wn*64 + nt*16 + lr];
    #pragma unroll
    for (int mt = 0; mt < 8; ++mt) {
      acc[mt][nt][0] = bz; acc[mt][nt][1] = bz;
      acc[mt][nt][2] = bz; acc[mt][nt][3] = bz;
    }
  }

  stage_A_l2(lds, u16, v16, bi0, b, 0, t);
  stage_W(lds + 65536, w2h, colbase, 0, t);
  __syncthreads();
  for (int s = 0; s < 8; ++s) {
    const int cur = s & 1;
    if (s < 7) {
      stage_A_l2(lds + (cur^1)*32768, u16, v16, bi0, b, s+1, t);
      stage_W(lds + 65536 + (cur^1)*32768, w2h, colbase, s+1, t);
    }
    compute_step(lds + cur*32768, lds + 65536 + cur*32768, wm, wn, lr, lg, acc);
    __syncthreads();
  }

  // repack H2 tile to LDS (swizzle slot = (row>>2)&7 to spread lg-groups),
  // then coalesced 16B global stores
  #pragma unroll
  for (int mt = 0; mt < 8; ++mt)
    #pragma unroll
    for (int nt = 0; nt < 4; ++nt)
      #pragma unroll
      for (int r = 0; r < 4; ++r) {
        int rr = wm*128 + mt*16 + lg*4 + r;
        int cc = wn*64 + nt*16 + lr;
        *(_Float16*)(lds + ((rr*512 + cc*2) ^ (((rr >> 2) & 7) << 4))) =
            (_Float16)fmaxf(acc[mt][nt][r], 0.0f);
      }
  __syncthreads();
  #pragma unroll
  for (int p = 0; p < 16; ++p) {
    int q = p*512 + t;
    int rr = q >> 5, c8 = q & 31;
    f16x8 hv = *(const f16x8*)(lds + ((rr*512 + c8*16) ^ (((rr >> 2) & 7) << 4)));
    *(f16x8*)(h2g + (size_t)(mrel + rr)*NH + colbase + c8*8) = hv;
  }
}

__global__ __launch_bounds__(512, 1) void edge_l3(
    const _Float16* __restrict__ h2g, const _Float16* __restrict__ w3h,
    const float* __restrict__ e3b, const float* __restrict__ maskp,
    const float* __restrict__ cntp, float* __restrict__ agg, int row0) {
  __shared__ __align__(16) char lds[131072];
  __shared__ float em_s[64];
  const int t = threadIdx.x;
  const int mrel = blockIdx.x * 256;
  const int bi0 = (row0 + mrel) >> 6;
  const int b = bi0 >> 6;
  const int colbase = blockIdx.y * 256;
  const int w = t >> 6, l = t & 63, lr = l & 15, lg = l >> 4;
  const int wm = w >> 2, wn = w & 3;

  if (t < 64) em_s[t] = maskp[(size_t)b*64 + t];

  f32x4 acc[8][4];
  #pragma unroll
  for (int nt = 0; nt < 4; ++nt) {
    float bz = e3b[colbase + wn*64 + nt*16 + lr];
    #pragma unroll
    for (int mt = 0; mt < 8; ++mt) {
      acc[mt][nt][0] = bz; acc[mt][nt][1] = bz;
      acc[mt][nt][2] = bz; acc[mt][nt][3] = bz;
    }
  }

  stage_H2(lds, h2g, mrel, 0, t);
  stage_W(lds + 65536, w3h, colbase, 0, t);
  __syncthreads();
  for (int s = 0; s < 8; ++s) {
    const int cur = s & 1;
    if (s < 7) {
      stage_H2(lds + (cur^1)*32768, h2g, mrel, s+1, t);
      stage_W(lds + 65536 + (cur^1)*32768, w3h, colbase, s+1, t);
    }
    compute_step(lds + cur*32768, lds + 65536 + cur*32768, wm, wn, lr, lg, acc);
    __syncthreads();
  }

  // relu + mask-weighted sum over j (rows within each bi group of 64)
  float csum[2][4] = {{0.f,0.f,0.f,0.f},{0.f,0.f,0.f,0.f}};
  #pragma unroll
  for (int mt = 0; mt < 8; ++mt) {
    const int g = mt >> 2;
    float em0 = em_s[(mt&3)*16 + lg*4 + 0];
    float em1 = em_s[(mt&3)*16 + lg*4 + 1];
    float em2 = em_s[(mt&3)*16 + lg*4 + 2];
    float em3 = em_s[(mt&3)*16 + lg*4 + 3];
    #pragma unroll
    for (int nt = 0; nt < 4; ++nt) {
      csum[g][nt] += em0 * fmaxf(acc[mt][nt][0], 0.f)
                   + em1 * fmaxf(acc[mt][nt][1], 0.f)
                   + em2 * fmaxf(acc[mt][nt][2], 0.f)
                   + em3 * fmaxf(acc[mt][nt][3], 0.f);
    }
  }
  #pragma unroll
  for (int g = 0; g < 2; ++g)
    #pragma unroll
    for (int nt = 0; nt < 4; ++nt) {
      csum[g][nt] += __shfl_xor(csum[g][nt], 16);
      csum[g][nt] += __shfl_xor(csum[g][nt], 32);
    }
  float cnt = cntp[b];
  if (lg == 0) {
    #pragma unroll
    for (int g = 0; g < 2; ++g) {
      int big = bi0 + wm*2 + g;
      float sc = em_s[big & 63] / cnt;
      #pragma unroll
      for (int nt = 0; nt < 4; ++nt)
        agg[(size_t)big*NH + colbase + wn*64 + nt*16 + lr] = csum[g][nt] * sc;
    }
  }
}

__global__ __launch_bounds__(256) void ln_kernel(
    const float* __restrict__ agg, const float* __restrict__ lng,
    const float* __restrict__ lnb, _Float16* __restrict__ nodein) {
  const int w = threadIdx.x >> 6, l = threadIdx.x & 63;
  const int row = blockIdx.x*4 + w;
  const float* ar = agg + (size_t)row*NH + l*8;
  float4 a0 = *(const float4*)ar;
  float4 a1 = *(const float4*)(ar + 4);
  float s1 = a0.x + a0.y + a0.z + a0.w + a1.x + a1.y + a1.z + a1.w;
  float s2 = a0.x*a0.x + a0.y*a0.y + a0.z*a0.z + a0.w*a0.w
           + a1.x*a1.x + a1.y*a1.y + a1.z*a1.z + a1.w*a1.w;
  #pragma unroll
  for (int off = 1; off < 64; off <<= 1) {
    s1 += __shfl_xor(s1, off);
    s2 += __shfl_xor(s2, off);
  }
  float mean = s1 * (1.0f/512.0f);
  float rstd = rsqrtf(s2 * (1.0f/512.0f) - mean*mean + 1e-5f);
  float4 g0 = *(const float4*)(lng + l*8);
  float4 g1 = *(const float4*)(lng + l*8 + 4);
  float4 b0 = *(const float4*)(lnb + l*8);
  float4 b1 = *(const float4*)(lnb + l*8 + 4);
  f16x4 o0, o1;
  o0[0] = (_Float16)((a0.x - mean) * rstd * g0.x + b0.x);
  o0[1] = (_Float16)((a0.y - mean) * rstd * g0.y + b0.y);
  o0[2] = (_Float16)((a0.z - mean) * rstd * g0.z + b0.z);
  o0[3] = (_Float16)((a0.w - mean) * rstd * g0.w + b0.w);
  o1[0] = (_Float16)((a1.x - mean) * rstd * g1.x + b1.x);
  o1[1] = (_Float16)((a1.y - mean) * rstd * g1.y + b1.y);
  o1[2] = (_Float16)((a1.z - mean) * rstd * g1.z + b1.z);
  o1[3] = (_Float16)((a1.w - mean) * rstd * g1.w + b1.w);
  _Float16* nr = nodein + (size_t)row*NKP + 4 + l*8;
  *(f16x4*)nr = o0;
  *(f16x4*)(nr + 4) = o1;
}

// ---------------------------------------------------------------- node ----

template <int RELU16>
__global__ __launch_bounds__(256) void node_gemm(
    const _Float16* __restrict__ A, const _Float16* __restrict__ Bw,
    const float* __restrict__ bias, void* __restrict__ outp,
    int Ka, int ldo) {
  const int t = threadIdx.x;
  const int w = t >> 6, l = t & 63, lr = l & 15, lg = l >> 4;
  const int m0 = blockIdx.x * 64;
  const int col = blockIdx.y * 64 + w*16 + lr;
  f32x4 acc[4];
  float bz = bias[col];
  #pragma unroll
  for (int mt = 0; mt < 4; ++mt) {
    acc[mt][0] = bz; acc[mt][1] = bz; acc[mt][2] = bz; acc[mt][3] = bz;
  }
  const _Float16* bptr = Bw + (size_t)col*Ka + lg*8;
  const _Float16* aptr = A + (size_t)(m0 + lr)*Ka + lg*8;
  const int nkk = Ka >> 5;
  for (int kk = 0; kk < nkk; ++kk) {
    f16x8 bf = *(const f16x8*)(bptr + kk*32);
    #pragma unroll
    for (int mt = 0; mt < 4; ++mt) {
      f16x8 af = *(const f16x8*)(aptr + ((size_t)mt*16)*Ka + kk*32);
      acc[mt] = __builtin_amdgcn_mfma_f32_16x16x32_f16(af, bf, acc[mt], 0, 0, 0);
    }
  }
  #pragma unroll
  for (int mt = 0; mt < 4; ++mt)
    #pragma unroll
    for (int r = 0; r < 4; ++r) {
      int row = m0 + mt*16 + lg*4 + r;
      float vv = acc[mt][r];
      if (RELU16)
        ((_Float16*)outp)[(size_t)row*ldo + col] = (_Float16)fmaxf(vv, 0.f);
      else
        ((float*)outp)[(size_t)row*ldo + col] = vv;
    }
}

// ----------------------------------------------------------- pool/heads ----

__global__ __launch_bounds__(256) void pool_kernel(
    const float* __restrict__ nodeout, const float* __restrict__ maskp,
    const float* __restrict__ cntp, float* __restrict__ xfeat) {
  const int b = blockIdx.x;
  const int c = threadIdx.x;  // 256
  float sum = 0.f, mx = -1e9f;
  for (int i = 0; i < 64; ++i) {
    float m = maskp[b*64 + i];
    float v = nodeout[((size_t)(b*64 + i))*256 + c];
    sum += m * v;
    mx = fmaxf(mx, (m != 0.f) ? v : -1e9f);
  }
  xfeat[b*1024 + 512 + c] = sum / cntp[b];
  xfeat[b*1024 + 768 + c] = mx;
}

__global__ __launch_bounds__(512) void heads_kernel(
    const float* __restrict__ xfeat,
    const float* __restrict__ mu1w, const float* __restrict__ mu1b,
    const float* __restrict__ mu2w, const float* __restrict__ mu2b,
    const float* __restrict__ mu3w, const float* __restrict__ mu3b,
    const float* __restrict__ s1w, const float* __restrict__ s1b,
    const float* __restrict__ s2w, const float* __restrict__ s2b,
    const float* __restrict__ s3w, const float* __restrict__ s3b,
    float* __restrict__ outp) {
  __shared__ __align__(16) float xs[1024];
  __shared__ __align__(16) float h1[512];
  __shared__ __align__(16) float h2[256];
  const int b = blockIdx.x;
  const int t = threadIdx.x;
  xs[t] = xfeat[b*1024 + t];
  xs[t + 512] = xfeat[b*1024 + 512 + t];
  __syncthreads();
  {
    const int oo = t & 255;
    const bool sp = t >= 256;
    const float* wr = (sp ? s1w : mu1w) + (size_t)oo*1024;
    float a = (sp ? s1b : mu1b)[oo];
    for (int k = 0; k < 1024; k += 4) {
      float4 ww = *(const float4*)(wr + k);
      float4 xx = *(const float4*)(xs + k);
      a += ww.x*xx.x + ww.y*xx.y + ww.z*xx.z + ww.w*xx.w;
    }
    h1[(sp ? 256 : 0) + oo] = fmaxf(a, 0.f);
  }
  __syncthreads();
  if (t < 256) {
    const int oo = t & 127;
    const bool sp = t >= 128;
    const float* wr = (sp ? s2w : mu2w) + (size_t)oo*256;
    const float* hbp = h1 + (sp ? 256 : 0);
    float a = (sp ? s2b : mu2b)[oo];
    for (int k = 0; k < 256; k += 4) {
      float4 ww = *(const float4*)(wr + k);
      float4 hh = *(const float4*)(hbp + k);
      a += ww.x*hh.x + ww.y*hh.y + ww.z*hh.z + ww.w*hh.w;
    }
    h2[(sp ? 128 : 0) + oo] = fmaxf(a, 0.f);
  }
  __syncthreads();
  if (t < 4) {
    const int oo = t & 1;
    const bool sp = t >= 2;
    const float* wr = (sp ? s3w : mu3w) + oo*128;
    const float* hbp = h2 + (sp ? 128 : 0);
    float a = (sp ? s3b : mu3b)[oo];
    for (int k = 0; k < 128; ++k) a += wr[k] * hbp[k];
    if (!sp) {
      outp[b*2 + oo] = a;
    } else {
      float spv = (a > 0.f) ? (a + log1pf(expf(-a))) : log1pf(expf(a));
      float sd = fminf(fmaxf(spv + 0.001f, 0.1f), 2.0f);
      outp[64 + b*2 + oo] = sd;
    }
  }
}

// --------------------------------------------------------------- launch ----

extern "C" void kernel_launch(void* const* d_in, const int* in_sizes, int n_in,
                              void* d_out, int out_size, void* d_ws, size_t ws_size,
                              hipStream_t stream) {
  const float* state  = (const float*)d_in[0];
  const float* obs    = (const float*)d_in[1];
  const float* layerw = (const float*)d_in[2];
  const float* layerb = (const float*)d_in[3];
  const float* e1w    = (const float*)d_in[4];
  const float* e1b    = (const float*)d_in[5];
  const float* e2w    = (const float*)d_in[6];
  const float* e2b    = (const float*)d_in[7];
  const float* e3w    = (const float*)d_in[8];
  const float* e3b    = (const float*)d_in[9];
  const float* lng    = (const float*)d_in[10];
  const float* lnb    = (const float*)d_in[11];
  const float* n1w    = (const float*)d_in[12];
  const float* n1b    = (const float*)d_in[13];
  const float* n2w    = (const float*)d_in[14];
  const float* n2b    = (const float*)d_in[15];
  const float* mu1w   = (const float*)d_in[16];
  const float* mu1b   = (const float*)d_in[17];
  const float* mu2w   = (const float*)d_in[18];
  const float* mu2b   = (const float*)d_in[19];
  const float* mu3w   = (const float*)d_in[20];
  const float* mu3b   = (const float*)d_in[21];
  const float* s1w    = (const float*)d_in[22];
  const float* s1b    = (const float*)d_in[23];
  const float* s2w    = (const float*)d_in[24];
  const float* s2b    = (const float*)d_in[25];
  const float* s3w    = (const float*)d_in[26];
  const float* s3b    = (const float*)d_in[27];
  float* outp = (float*)d_out;

  char* p = (char*)d_ws;
  auto alloc = [&](size_t bytes) {
    char* r = p;
    p += (bytes + 255) & ~(size_t)255;
    return r;
  };
  float*    o       = (float*)alloc((size_t)2048*4*4);
  float*    maskp   = (float*)alloc((size_t)2048*4);
  float*    cntp    = (float*)alloc((size_t)32*4);
  _Float16* u16     = (_Float16*)alloc((size_t)2048*512*2);
  _Float16* v16     = (_Float16*)alloc((size_t)2048*512*2);
  _Float16* w2h     = (_Float16*)alloc((size_t)512*512*2);
  _Float16* w3h     = (_Float16*)alloc((size_t)512*512*2);
  _Float16* nodein  = (_Float16*)alloc((size_t)2048*544*2);
  _Float16* n1wh    = (_Float16*)alloc((size_t)512*544*2);
  _Float16* n2wh    = (_Float16*)alloc((size_t)256*512*2);
  _Float16* nodeh   = (_Float16*)alloc((size_t)2048*512*2);
  float*    nodeout = (float*)alloc((size_t)2048*256*4);
  float*    xfeat   = (float*)alloc((size_t)32*1024*4);
  float*    agg     = (float*)alloc((size_t)2048*512*4);

  // H2 chunk buffer: as large as ws allows, up to 32768 rows (32 MB)
  size_t used = (size_t)(p - (char*)d_ws);
  size_t avail = (ws_size > used) ? (ws_size - used) : 0;
  int chunk = 32768;
  while (chunk > 2048 && (size_t)chunk * 1024 + 256 > avail) chunk >>= 1;
  _Float16* h2g = (_Float16*)alloc((size_t)chunk * 512 * 2);

  prep_obs_kernel<<<32, 64, 0, stream>>>(obs, state, o, maskp, cntp, nodein);
  prep_uv16<<<2048, 512, 0, stream>>>(o, e1w, e1b, u16, v16);
  prep_w16_kernel<<<3648, 256, 0, stream>>>(e2w, e3w, n2w, n1w, w2h, w3h, n2wh, n1wh);
  prep_stfeat_kernel<<<32, 512, 0, stream>>>(state, layerw, layerb, xfeat);

  const int mtiles = chunk / 256;
  for (int row0 = 0; row0 < RTOT; row0 += chunk) {
    edge_l2<<<dim3(mtiles, 2), 512, 0, stream>>>(u16, v16, w2h, e2b, h2g, row0);
    edge_l3<<<dim3(mtiles, 2), 512, 0, stream>>>(h2g, w3h, e3b, maskp, cntp, agg, row0);
  }
  ln_kernel<<<512, 256, 0, stream>>>(agg, lng, lnb, nodein);

  node_gemm<1><<<dim3(32, 8), 256, 0, stream>>>(nodein, n1wh, n1b, (void*)nodeh, 544, 512);
  node_gemm<0><<<dim3(32, 4), 256, 0, stream>>>(nodeh, n2wh, n2b, (void*)nodeout, 512, 256);
  pool_kernel<<<32, 256, 0, stream>>>(nodeout, maskp, cntp, xfeat);
  heads_kernel<<<32, 512, 0, stream>>>(xfeat, mu1w, mu1b, mu2w, mu2b, mu3w, mu3b,
                                       s1w, s1b, s2w, s2b, s3w, s3b, outp);
}

// Round 3
// 291.353 us; speedup vs baseline: 1.4450x; 1.1786x over previous
//
#include <hip/hip_runtime.h>
#include <hip/hip_fp16.h>

typedef _Float16 f16x8 __attribute__((ext_vector_type(8)));
typedef _Float16 f16x4 __attribute__((ext_vector_type(4)));
typedef float f32x4 __attribute__((ext_vector_type(4)));

#define NB 32
#define NK 64
#define ND 4
#define NH 512
#define NKP 544   // node-input K (520) padded to 17*32
#define RTOT 131072

// ---------------------------------------------------------------- prep ----

__global__ void prep_obs_kernel(const float* __restrict__ obs,
                                const float* __restrict__ state,
                                float* __restrict__ o,
                                float* __restrict__ maskp,
                                float* __restrict__ cntp,
                                _Float16* __restrict__ nodein) {
  const int b = blockIdx.x;
  const int j = threadIdx.x;  // 64
  float o0 = obs[(b*4 + 0)*64 + j];
  float o1 = obs[(b*4 + 1)*64 + j];
  float o2 = obs[(b*4 + 2)*64 + j];
  float o3 = obs[(b*4 + 3)*64 + j];
  size_t bi = (size_t)b*64 + j;
  float* orow = o + bi*4;
  orow[0] = o0; orow[1] = o1; orow[2] = o2; orow[3] = o3;
  float s = fabsf(o0) + fabsf(o1) + fabsf(o2) + fabsf(o3);
  float m = (s != 0.0f) ? 1.0f : 0.0f;
  maskp[bi] = m;
  float c = m;
  #pragma unroll
  for (int off = 1; off < 64; off <<= 1) c += __shfl_xor(c, off);
  if (j == 0) cntp[b] = fmaxf(c, 1e-6f);
  _Float16* nrow = nodein + bi*NKP;
  nrow[0] = (_Float16)o0; nrow[1] = (_Float16)o1;
  nrow[2] = (_Float16)o2; nrow[3] = (_Float16)o3;
  nrow[516] = (_Float16)state[b*4 + 0];
  nrow[517] = (_Float16)state[b*4 + 1];
  nrow[518] = (_Float16)state[b*4 + 2];
  nrow[519] = (_Float16)state[b*4 + 3];
  for (int k2 = 520; k2 < 544; ++k2) nrow[k2] = (_Float16)0.0f;
}

// u16[bi][c] = W1[:, :4]·o_bi + b1  (f16);  v16[bi][c] = W1[:, 4:]·o_bi (f16)
__global__ void prep_uv16(const float* __restrict__ o,
                          const float* __restrict__ e1w,
                          const float* __restrict__ e1b,
                          _Float16* __restrict__ u16,
                          _Float16* __restrict__ v16) {
  const int bi = blockIdx.x;     // 2048
  const int c = threadIdx.x;     // 512
  const float* orow = o + (size_t)bi*4;
  float o0 = orow[0], o1 = orow[1], o2 = orow[2], o3 = orow[3];
  const float* wr = e1w + c*8;
  float u = wr[0]*o0 + wr[1]*o1 + wr[2]*o2 + wr[3]*o3 + e1b[c];
  float v = wr[4]*o0 + wr[5]*o1 + wr[6]*o2 + wr[7]*o3;
  u16[(size_t)bi*NH + c] = (_Float16)u;
  v16[(size_t)bi*NH + c] = (_Float16)v;
}

__global__ void prep_w16_kernel(const float* __restrict__ e2w,
                                const float* __restrict__ e3w,
                                const float* __restrict__ n2w,
                                const float* __restrict__ n1w,
                                _Float16* __restrict__ w2h,
                                _Float16* __restrict__ w3h,
                                _Float16* __restrict__ n2wh,
                                _Float16* __restrict__ n1wh) {
  int idx = blockIdx.x * blockDim.x + threadIdx.x;
  const int A = 512*512, Bc = 512*512, C = 256*512, Dn = 512*544;
  if (idx < A) {
    w2h[idx] = (_Float16)e2w[idx];
  } else if (idx < A + Bc) {
    int q = idx - A; w3h[q] = (_Float16)e3w[q];
  } else if (idx < A + Bc + C) {
    int q = idx - A - Bc; n2wh[q] = (_Float16)n2w[q];
  } else if (idx < A + Bc + C + Dn) {
    int q = idx - A - Bc - C;
    int n = q / 544, k = q % 544;
    n1wh[q] = (k < 520) ? (_Float16)n1w[n*520 + k] : (_Float16)0.0f;
  }
}

__global__ void prep_stfeat_kernel(const float* __restrict__ state,
                                   const float* __restrict__ lw,
                                   const float* __restrict__ lb,
                                   float* __restrict__ xfeat) {
  const int b = blockIdx.x, c = threadIdx.x;  // 512
  const float* s = state + b*4;
  const float* wr = lw + c*4;
  float hv = wr[0]*s[0] + wr[1]*s[1] + wr[2]*s[2] + wr[3]*s[3] + lb[c];
  xfeat[b*1024 + c] = fmaxf(hv, 0.0f);
}

// ------------------------------------------------------- edge (2 GEMMs) ----
// Geometry: WG tile 256 (rows) x 256 (cols), K=512 in 8 steps of 64.
// 512 threads = 8 waves, 2M x 4N, wave tile 128x64, acc[8][4] f32x4.
// LDS 128 KB: A0 @0, A1 @32768, B0 @65536, B1 @98304 (256x64 f16 each,
// XOR-swizzled: byte = (row*128 + kc*16) ^ ((row&7)<<4)).

__device__ __forceinline__ void stage_A_l2(char* abuf,
                                           const _Float16* __restrict__ u16,
                                           const _Float16* __restrict__ v16,
                                           int bi0, int b, int s, int t) {
  const int tr = t >> 3, kc = t & 7;
  const int kof = s*64 + kc*8;
  f16x8 vv = *(const f16x8*)(v16 + (size_t)(b*64 + tr)*NH + kof);
  #pragma unroll
  for (int p = 0; p < 4; ++p) {
    f16x8 uu = *(const f16x8*)(u16 + (size_t)(bi0 + p)*NH + kof);
    f16x8 hv;
    #pragma unroll
    for (int e = 0; e < 8; ++e) {
      _Float16 x = uu[e] + vv[e];
      hv[e] = x > (_Float16)0 ? x : (_Float16)0;
    }
    int rr = p*64 + tr;
    *(f16x8*)(abuf + ((rr*128 + kc*16) ^ ((rr & 7) << 4))) = hv;
  }
}

__device__ __forceinline__ void stage_W(char* bbuf,
                                        const _Float16* __restrict__ w,
                                        int colbase, int s, int t) {
  const int tr = t >> 3, kc = t & 7;
  const int kof = s*64 + kc*8;
  #pragma unroll
  for (int p = 0; p < 4; ++p) {
    int rr = p*64 + tr;
    f16x8 wv = *(const f16x8*)(w + (size_t)(colbase + rr)*NH + kof);
    *(f16x8*)(bbuf + ((rr*128 + kc*16) ^ ((rr & 7) << 4))) = wv;
  }
}

__device__ __forceinline__ void stage_H2(char* abuf,
                                         const _Float16* __restrict__ h2g,
                                         int mrel, int s, int t) {
  const int tr = t >> 3, kc = t & 7;
  const int kof = s*64 + kc*8;
  #pragma unroll
  for (int p = 0; p < 4; ++p) {
    int rr = p*64 + tr;
    f16x8 hv = *(const f16x8*)(h2g + (size_t)(mrel + rr)*NH + kof);
    *(f16x8*)(abuf + ((rr*128 + kc*16) ^ ((rr & 7) << 4))) = hv;
  }
}

__device__ __forceinline__ void compute_step(const char* abuf, const char* bbuf,
                                             int wm, int wn, int lr, int lg,
                                             f32x4 acc[8][4]) {
  #pragma unroll
  for (int kk = 0; kk < 2; ++kk) {
    const int sl = kk*4 + lg;
    f16x8 bf[4];
    #pragma unroll
    for (int nt = 0; nt < 4; ++nt) {
      int rb = wn*64 + nt*16 + lr;
      bf[nt] = *(const f16x8*)(bbuf + ((rb*128 + sl*16) ^ ((rb & 7) << 4)));
    }
    #pragma unroll
    for (int mt = 0; mt < 8; ++mt) {
      int ra = wm*128 + mt*16 + lr;
      f16x8 af = *(const f16x8*)(abuf + ((ra*128 + sl*16) ^ ((ra & 7) << 4)));
      #pragma unroll
      for (int nt = 0; nt < 4; ++nt)
        acc[mt][nt] = __builtin_amdgcn_mfma_f32_16x16x32_f16(af, bf[nt], acc[mt][nt], 0, 0, 0);
    }
  }
}

__global__ __launch_bounds__(512, 1) void edge_l2(
    const _Float16* __restrict__ u16, const _Float16* __restrict__ v16,
    const _Float16* __restrict__ w2h, const float* __restrict__ e2b,
    _Float16* __restrict__ h2g, int row0) {
  __shared__ __align__(16) char lds[131072];
  const int t = threadIdx.x;
  const int mrel = blockIdx.x * 256;
  const int rowbase = row0 + mrel;
  const int bi0 = rowbase >> 6;     // 4 consecutive bi, same b
  const int b = bi0 >> 6;
  const int colbase = blockIdx.y * 256;
  const int w = t >> 6, l = t & 63, lr = l & 15, lg = l >> 4;
  const int wm = w >> 2, wn = w & 3;

  f32x4 acc[8][4];
  #pragma unroll
  for (int nt = 0; nt < 4; ++nt) {
    float bz = e2b[colbase + wn*64 + nt*16 + lr];
    #pragma unroll
    for (int mt = 0; mt < 8; ++mt) {
      acc[mt][nt][0] = bz; acc[mt][nt][1] = bz;
      acc[mt][nt][2] = bz; acc[mt][nt][3] = bz;
    }
  }

  stage_A_l2(lds, u16, v16, bi0, b, 0, t);
  stage_W(lds + 65536, w2h, colbase, 0, t);
  __syncthreads();
  for (int s = 0; s < 8; ++s) {
    const int cur = s & 1;
    if (s < 7) {
      stage_A_l2(lds + (cur^1)*32768, u16, v16, bi0, b, s+1, t);
      stage_W(lds + 65536 + (cur^1)*32768, w2h, colbase, s+1, t);
    }
    compute_step(lds + cur*32768, lds + 65536 + cur*32768, wm, wn, lr, lg, acc);
    __syncthreads();
  }

  // repack H2 tile to LDS (swizzle slot = (row>>2)&7 to spread lg-groups),
  // then coalesced 16B global stores
  #pragma unroll
  for (int mt = 0; mt < 8; ++mt)
    #pragma unroll
    for (int nt = 0; nt < 4; ++nt)
      #pragma unroll
      for (int r = 0; r < 4; ++r) {
        int rr = wm*128 + mt*16 + lg*4 + r;
        int cc = wn*64 + nt*16 + lr;
        *(_Float16*)(lds + ((rr*512 + cc*2) ^ (((rr >> 2) & 7) << 4))) =
            (_Float16)fmaxf(acc[mt][nt][r], 0.0f);
      }
  __syncthreads();
  #pragma unroll
  for (int p = 0; p < 16; ++p) {
    int q = p*512 + t;
    int rr = q >> 5, c8 = q & 31;
    f16x8 hv = *(const f16x8*)(lds + ((rr*512 + c8*16) ^ (((rr >> 2) & 7) << 4)));
    *(f16x8*)(h2g + (size_t)(mrel + rr)*NH + colbase + c8*8) = hv;
  }
}

__global__ __launch_bounds__(512, 1) void edge_l3(
    const _Float16* __restrict__ h2g, const _Float16* __restrict__ w3h,
    const float* __restrict__ e3b, const float* __restrict__ maskp,
    const float* __restrict__ cntp, float* __restrict__ agg, int row0) {
  __shared__ __align__(16) char lds[131072];
  __shared__ float em_s[64];
  const int t = threadIdx.x;
  const int mrel = blockIdx.x * 256;
  const int bi0 = (row0 + mrel) >> 6;
  const int b = bi0 >> 6;
  const int colbase = blockIdx.y * 256;
  const int w = t >> 6, l = t & 63, lr = l & 15, lg = l >> 4;
  const int wm = w >> 2, wn = w & 3;

  if (t < 64) em_s[t] = maskp[(size_t)b*64 + t];

  f32x4 acc[8][4];
  #pragma unroll
  for (int nt = 0; nt < 4; ++nt) {
    float bz = e3b[colbase + wn*64 + nt*16 + lr];
    #pragma unroll
    for (int mt = 0; mt < 8; ++mt) {
      acc[mt][nt][0] = bz; acc[mt][nt][1] = bz;
      acc[mt][nt][2] = bz; acc[mt][nt][3] = bz;
    }
  }

  stage_H2(lds, h2g, mrel, 0, t);
  stage_W(lds + 65536, w3h, colbase, 0, t);
  __syncthreads();
  for (int s = 0; s < 8; ++s) {
    const int cur = s & 1;
    if (s < 7) {
      stage_H2(lds + (cur^1)*32768, h2g, mrel, s+1, t);
      stage_W(lds + 65536 + (cur^1)*32768, w3h, colbase, s+1, t);
    }
    compute_step(lds + cur*32768, lds + 65536 + cur*32768, wm, wn, lr, lg, acc);
    __syncthreads();
  }

  // relu + mask-weighted sum over j (rows within each bi group of 64)
  float csum[2][4] = {{0.f,0.f,0.f,0.f},{0.f,0.f,0.f,0.f}};
  #pragma unroll
  for (int mt = 0; mt < 8; ++mt) {
    const int g = mt >> 2;
    float em0 = em_s[(mt&3)*16 + lg*4 + 0];
    float em1 = em_s[(mt&3)*16 + lg*4 + 1];
    float em2 = em_s[(mt&3)*16 + lg*4 + 2];
    float em3 = em_s[(mt&3)*16 + lg*4 + 3];
    #pragma unroll
    for (int nt = 0; nt < 4; ++nt) {
      csum[g][nt] += em0 * fmaxf(acc[mt][nt][0], 0.f)
                   + em1 * fmaxf(acc[mt][nt][1], 0.f)
                   + em2 * fmaxf(acc[mt][nt][2], 0.f)
                   + em3 * fmaxf(acc[mt][nt][3], 0.f);
    }
  }
  #pragma unroll
  for (int g = 0; g < 2; ++g)
    #pragma unroll
    for (int nt = 0; nt < 4; ++nt) {
      csum[g][nt] += __shfl_xor(csum[g][nt], 16);
      csum[g][nt] += __shfl_xor(csum[g][nt], 32);
    }
  float cnt = cntp[b];
  if (lg == 0) {
    #pragma unroll
    for (int g = 0; g < 2; ++g) {
      int big = bi0 + wm*2 + g;
      float sc = em_s[big & 63] / cnt;
      #pragma unroll
      for (int nt = 0; nt < 4; ++nt)
        agg[(size_t)big*NH + colbase + wn*64 + nt*16 + lr] = csum[g][nt] * sc;
    }
  }
}

__global__ __launch_bounds__(256) void ln_kernel(
    const float* __restrict__ agg, const float* __restrict__ lng,
    const float* __restrict__ lnb, _Float16* __restrict__ nodein) {
  const int w = threadIdx.x >> 6, l = threadIdx.x & 63;
  const int row = blockIdx.x*4 + w;
  const float* ar = agg + (size_t)row*NH + l*8;
  float4 a0 = *(const float4*)ar;
  float4 a1 = *(const float4*)(ar + 4);
  float s1 = a0.x + a0.y + a0.z + a0.w + a1.x + a1.y + a1.z + a1.w;
  float s2 = a0.x*a0.x + a0.y*a0.y + a0.z*a0.z + a0.w*a0.w
           + a1.x*a1.x + a1.y*a1.y + a1.z*a1.z + a1.w*a1.w;
  #pragma unroll
  for (int off = 1; off < 64; off <<= 1) {
    s1 += __shfl_xor(s1, off);
    s2 += __shfl_xor(s2, off);
  }
  float mean = s1 * (1.0f/512.0f);
  float rstd = rsqrtf(s2 * (1.0f/512.0f) - mean*mean + 1e-5f);
  float4 g0 = *(const float4*)(lng + l*8);
  float4 g1 = *(const float4*)(lng + l*8 + 4);
  float4 b0 = *(const float4*)(lnb + l*8);
  float4 b1 = *(const float4*)(lnb + l*8 + 4);
  f16x4 o0, o1;
  o0[0] = (_Float16)((a0.x - mean) * rstd * g0.x + b0.x);
  o0[1] = (_Float16)((a0.y - mean) * rstd * g0.y + b0.y);
  o0[2] = (_Float16)((a0.z - mean) * rstd * g0.z + b0.z);
  o0[3] = (_Float16)((a0.w - mean) * rstd * g0.w + b0.w);
  o1[0] = (_Float16)((a1.x - mean) * rstd * g1.x + b1.x);
  o1[1] = (_Float16)((a1.y - mean) * rstd * g1.y + b1.y);
  o1[2] = (_Float16)((a1.z - mean) * rstd * g1.z + b1.z);
  o1[3] = (_Float16)((a1.w - mean) * rstd * g1.w + b1.w);
  _Float16* nr = nodein + (size_t)row*NKP + 4 + l*8;
  *(f16x4*)nr = o0;
  *(f16x4*)(nr + 4) = o1;
}

// ---------------------------------------------------------------- node ----

template <int RELU16>
__global__ __launch_bounds__(256) void node_gemm(
    const _Float16* __restrict__ A, const _Float16* __restrict__ Bw,
    const float* __restrict__ bias, void* __restrict__ outp,
    int Ka, int ldo) {
  const int t = threadIdx.x;
  const int w = t >> 6, l = t & 63, lr = l & 15, lg = l >> 4;
  const int m0 = blockIdx.x * 64;
  const int col = blockIdx.y * 64 + w*16 + lr;
  f32x4 acc[4];
  float bz = bias[col];
  #pragma unroll
  for (int mt = 0; mt < 4; ++mt) {
    acc[mt][0] = bz; acc[mt][1] = bz; acc[mt][2] = bz; acc[mt][3] = bz;
  }
  const _Float16* bptr = Bw + (size_t)col*Ka + lg*8;
  const _Float16* aptr = A + (size_t)(m0 + lr)*Ka + lg*8;
  const int nkk = Ka >> 5;
  for (int kk = 0; kk < nkk; ++kk) {
    f16x8 bf = *(const f16x8*)(bptr + kk*32);
    #pragma unroll
    for (int mt = 0; mt < 4; ++mt) {
      f16x8 af = *(const f16x8*)(aptr + ((size_t)mt*16)*Ka + kk*32);
      acc[mt] = __builtin_amdgcn_mfma_f32_16x16x32_f16(af, bf, acc[mt], 0, 0, 0);
    }
  }
  #pragma unroll
  for (int mt = 0; mt < 4; ++mt)
    #pragma unroll
    for (int r = 0; r < 4; ++r) {
      int row = m0 + mt*16 + lg*4 + r;
      float vv = acc[mt][r];
      if (RELU16)
        ((_Float16*)outp)[(size_t)row*ldo + col] = (_Float16)fmaxf(vv, 0.f);
      else
        ((float*)outp)[(size_t)row*ldo + col] = vv;
    }
}

// ----------------------------------------------------------- pool/heads ----

__global__ __launch_bounds__(256) void pool_kernel(
    const float* __restrict__ nodeout, const float* __restrict__ maskp,
    const float* __restrict__ cntp, float* __restrict__ xfeat) {
  const int b = blockIdx.x;
  const int c = threadIdx.x;  // 256
  float sum = 0.f, mx = -1e9f;
  for (int i = 0; i < 64; ++i) {
    float m = maskp[b*64 + i];
    float v = nodeout[((size_t)(b*64 + i))*256 + c];
    sum += m * v;
    mx = fmaxf(mx, (m != 0.f) ? v : -1e9f);
  }
  xfeat[b*1024 + 512 + c] = sum / cntp[b];
  xfeat[b*1024 + 768 + c] = mx;
}

// heads stage 1: partial dots over a 256-wide K slice.
// grid (32 b, 2 head, 4 kslice), 256 threads; thread t = output index.
__global__ __launch_bounds__(256) void heads_g1(
    const float* __restrict__ xfeat,
    const float* __restrict__ mu1w, const float* __restrict__ s1w,
    float* __restrict__ part) {
  __shared__ __align__(16) float xs[256];
  const int b = blockIdx.x, h = blockIdx.y, ks = blockIdx.z;
  const int t = threadIdx.x;
  xs[t] = xfeat[b*1024 + ks*256 + t];
  __syncthreads();
  const float* wr = (h ? s1w : mu1w) + (size_t)t*1024 + ks*256;
  float a = 0.f;
  #pragma unroll 8
  for (int k = 0; k < 256; k += 4) {
    float4 ww = *(const float4*)(wr + k);
    float4 xx = *(const float4*)(xs + k);
    a += ww.x*xx.x + ww.y*xx.y + ww.z*xx.z + ww.w*xx.w;
  }
  part[(((size_t)(b*2 + h))*256 + t)*4 + ks] = a;
}

// heads stage 2+3: reduce partials -> h1 (relu), layer2 (paired lanes),
// layer3 + softplus. grid (32 b, 2 head), 256 threads.
__global__ __launch_bounds__(256) void heads_g23(
    const float* __restrict__ part,
    const float* __restrict__ mu1b, const float* __restrict__ s1b,
    const float* __restrict__ mu2w, const float* __restrict__ mu2b,
    const float* __restrict__ s2w, const float* __restrict__ s2b,
    const float* __restrict__ mu3w, const float* __restrict__ mu3b,
    const float* __restrict__ s3w, const float* __restrict__ s3b,
    float* __restrict__ outp) {
  __shared__ __align__(16) float h1s[256];
  __shared__ __align__(16) float h2s[128];
  const int b = blockIdx.x, h = blockIdx.y;
  const int t = threadIdx.x;
  {
    float4 pp = *(const float4*)(part + (((size_t)(b*2 + h))*256 + t)*4);
    float a = pp.x + pp.y + pp.z + pp.w + (h ? s1b : mu1b)[t];
    h1s[t] = fmaxf(a, 0.f);
  }
  __syncthreads();
  {
    const int o = t >> 1, half = t & 1;
    const float* wr = (h ? s2w : mu2w) + (size_t)o*256 + half*128;
    const float* hp = h1s + half*128;
    float a = 0.f;
    #pragma unroll 8
    for (int k = 0; k < 128; k += 4) {
      float4 ww = *(const float4*)(wr + k);
      float4 hh = *(const float4*)(hp + k);
      a += ww.x*hh.x + ww.y*hh.y + ww.z*hh.z + ww.w*hh.w;
    }
    a += __shfl_xor(a, 1);
    if (half == 0) h2s[o] = fmaxf(a + (h ? s2b : mu2b)[o], 0.f);
  }
  __syncthreads();
  if (t < 64) {
    const int o = t >> 5, lane = t & 31;   // 32 lanes per output
    const float* wr = (h ? s3w : mu3w) + o*128 + lane*4;
    const float* hp = h2s + lane*4;
    float4 ww = *(const float4*)wr;
    float4 hh = *(const float4*)hp;
    float a = ww.x*hh.x + ww.y*hh.y + ww.z*hh.z + ww.w*hh.w;
    #pragma unroll
    for (int off = 1; off < 32; off <<= 1) a += __shfl_xor(a, off);
    if (lane == 0) {
      a += (h ? s3b : mu3b)[o];
      if (h == 0) {
        outp[b*2 + o] = a;
      } else {
        float spv = (a > 0.f) ? (a + log1pf(expf(-a))) : log1pf(expf(a));
        outp[64 + b*2 + o] = fminf(fmaxf(spv + 0.001f, 0.1f), 2.0f);
      }
    }
  }
}

// --------------------------------------------------------------- launch ----

extern "C" void kernel_launch(void* const* d_in, const int* in_sizes, int n_in,
                              void* d_out, int out_size, void* d_ws, size_t ws_size,
                              hipStream_t stream) {
  const float* state  = (const float*)d_in[0];
  const float* obs    = (const float*)d_in[1];
  const float* layerw = (const float*)d_in[2];
  const float* layerb = (const float*)d_in[3];
  const float* e1w    = (const float*)d_in[4];
  const float* e1b    = (const float*)d_in[5];
  const float* e2w    = (const float*)d_in[6];
  const float* e2b    = (const float*)d_in[7];
  const float* e3w    = (const float*)d_in[8];
  const float* e3b    = (const float*)d_in[9];
  const float* lng    = (const float*)d_in[10];
  const float* lnb    = (const float*)d_in[11];
  const float* n1w    = (const float*)d_in[12];
  const float* n1b    = (const float*)d_in[13];
  const float* n2w    = (const float*)d_in[14];
  const float* n2b    = (const float*)d_in[15];
  const float* mu1w   = (const float*)d_in[16];
  const float* mu1b   = (const float*)d_in[17];
  const float* mu2w   = (const float*)d_in[18];
  const float* mu2b   = (const float*)d_in[19];
  const float* mu3w   = (const float*)d_in[20];
  const float* mu3b   = (const float*)d_in[21];
  const float* s1w    = (const float*)d_in[22];
  const float* s1b    = (const float*)d_in[23];
  const float* s2w    = (const float*)d_in[24];
  const float* s2b    = (const float*)d_in[25];
  const float* s3w    = (const float*)d_in[26];
  const float* s3b    = (const float*)d_in[27];
  float* outp = (float*)d_out;

  char* p = (char*)d_ws;
  auto alloc = [&](size_t bytes) {
    char* r = p;
    p += (bytes + 255) & ~(size_t)255;
    return r;
  };
  float*    o       = (float*)alloc((size_t)2048*4*4);
  float*    maskp   = (float*)alloc((size_t)2048*4);
  float*    cntp    = (float*)alloc((size_t)32*4);
  _Float16* u16     = (_Float16*)alloc((size_t)2048*512*2);
  _Float16* v16     = (_Float16*)alloc((size_t)2048*512*2);
  _Float16* w2h     = (_Float16*)alloc((size_t)512*512*2);
  _Float16* w3h     = (_Float16*)alloc((size_t)512*512*2);
  _Float16* nodein  = (_Float16*)alloc((size_t)2048*544*2);
  _Float16* n1wh    = (_Float16*)alloc((size_t)512*544*2);
  _Float16* n2wh    = (_Float16*)alloc((size_t)256*512*2);
  _Float16* nodeh   = (_Float16*)alloc((size_t)2048*512*2);
  float*    nodeout = (float*)alloc((size_t)2048*256*4);
  float*    xfeat   = (float*)alloc((size_t)32*1024*4);
  float*    agg     = (float*)alloc((size_t)2048*512*4);
  float*    hpart   = (float*)alloc((size_t)32*2*256*4*4);

  // H2 chunk buffer: as large as ws allows, up to full 131072 rows (128 MB)
  size_t used = (size_t)(p - (char*)d_ws);
  size_t avail = (ws_size > used) ? (ws_size - used) : 0;
  int chunk = 131072;
  while (chunk > 2048 && (size_t)chunk * 1024 + 256 > avail) chunk >>= 1;
  _Float16* h2g = (_Float16*)alloc((size_t)chunk * 512 * 2);

  prep_obs_kernel<<<32, 64, 0, stream>>>(obs, state, o, maskp, cntp, nodein);
  prep_uv16<<<2048, 512, 0, stream>>>(o, e1w, e1b, u16, v16);
  prep_w16_kernel<<<3648, 256, 0, stream>>>(e2w, e3w, n2w, n1w, w2h, w3h, n2wh, n1wh);
  prep_stfeat_kernel<<<32, 512, 0, stream>>>(state, layerw, layerb, xfeat);

  const int mtiles = chunk / 256;
  for (int row0 = 0; row0 < RTOT; row0 += chunk) {
    edge_l2<<<dim3(mtiles, 2), 512, 0, stream>>>(u16, v16, w2h, e2b, h2g, row0);
    edge_l3<<<dim3(mtiles, 2), 512, 0, stream>>>(h2g, w3h, e3b, maskp, cntp, agg, row0);
  }
  ln_kernel<<<512, 256, 0, stream>>>(agg, lng, lnb, nodein);

  node_gemm<1><<<dim3(32, 8), 256, 0, stream>>>(nodein, n1wh, n1b, (void*)nodeh, 544, 512);
  node_gemm<0><<<dim3(32, 4), 256, 0, stream>>>(nodeh, n2wh, n2b, (void*)nodeout, 512, 256);
  pool_kernel<<<32, 256, 0, stream>>>(nodeout, maskp, cntp, xfeat);
  heads_g1<<<dim3(32, 2, 4), 256, 0, stream>>>(xfeat, mu1w, s1w, hpart);
  heads_g23<<<dim3(32, 2), 256, 0, stream>>>(hpart, mu1b, s1b, mu2w, mu2b,
                                             s2w, s2b, mu3w, mu3b, s3w, s3b, outp);
}

// Round 4
// 237.422 us; speedup vs baseline: 1.7732x; 1.2272x over previous
//
#include <hip/hip_runtime.h>
#include <hip/hip_fp16.h>

typedef _Float16 f16x8 __attribute__((ext_vector_type(8)));
typedef _Float16 f16x4 __attribute__((ext_vector_type(4)));
typedef float f32x4 __attribute__((ext_vector_type(4)));

#define NB 32
#define NK 64
#define ND 4
#define NH 512
#define NKP 544   // node-input K (520) padded to 17*32
#define RTOT 131072

// ---------------------------------------------------------------- prep ----

__global__ void prep_obs_kernel(const float* __restrict__ obs,
                                const float* __restrict__ state,
                                float* __restrict__ o,
                                float* __restrict__ maskp,
                                float* __restrict__ cntp,
                                _Float16* __restrict__ nodein) {
  const int b = blockIdx.x;
  const int j = threadIdx.x;  // 64
  float o0 = obs[(b*4 + 0)*64 + j];
  float o1 = obs[(b*4 + 1)*64 + j];
  float o2 = obs[(b*4 + 2)*64 + j];
  float o3 = obs[(b*4 + 3)*64 + j];
  size_t bi = (size_t)b*64 + j;
  float* orow = o + bi*4;
  orow[0] = o0; orow[1] = o1; orow[2] = o2; orow[3] = o3;
  float s = fabsf(o0) + fabsf(o1) + fabsf(o2) + fabsf(o3);
  float m = (s != 0.0f) ? 1.0f : 0.0f;
  maskp[bi] = m;
  float c = m;
  #pragma unroll
  for (int off = 1; off < 64; off <<= 1) c += __shfl_xor(c, off);
  if (j == 0) cntp[b] = fmaxf(c, 1e-6f);
  _Float16* nrow = nodein + bi*NKP;
  nrow[0] = (_Float16)o0; nrow[1] = (_Float16)o1;
  nrow[2] = (_Float16)o2; nrow[3] = (_Float16)o3;
  nrow[516] = (_Float16)state[b*4 + 0];
  nrow[517] = (_Float16)state[b*4 + 1];
  nrow[518] = (_Float16)state[b*4 + 2];
  nrow[519] = (_Float16)state[b*4 + 3];
  for (int k2 = 520; k2 < 544; ++k2) nrow[k2] = (_Float16)0.0f;
}

// u16[bi][c] = W1[:, :4]·o_bi + b1  (f16);  v16[bi][c] = W1[:, 4:]·o_bi (f16)
__global__ void prep_uv16(const float* __restrict__ o,
                          const float* __restrict__ e1w,
                          const float* __restrict__ e1b,
                          _Float16* __restrict__ u16,
                          _Float16* __restrict__ v16) {
  const int bi = blockIdx.x;     // 2048
  const int c = threadIdx.x;     // 512
  const float* orow = o + (size_t)bi*4;
  float o0 = orow[0], o1 = orow[1], o2 = orow[2], o3 = orow[3];
  const float* wr = e1w + c*8;
  float u = wr[0]*o0 + wr[1]*o1 + wr[2]*o2 + wr[3]*o3 + e1b[c];
  float v = wr[4]*o0 + wr[5]*o1 + wr[6]*o2 + wr[7]*o3;
  u16[(size_t)bi*NH + c] = (_Float16)u;
  v16[(size_t)bi*NH + c] = (_Float16)v;
}

__global__ void prep_w16_kernel(const float* __restrict__ e2w,
                                const float* __restrict__ e3w,
                                const float* __restrict__ n2w,
                                const float* __restrict__ n1w,
                                _Float16* __restrict__ w2h,
                                _Float16* __restrict__ w3h,
                                _Float16* __restrict__ n2wh,
                                _Float16* __restrict__ n1wh) {
  int idx = blockIdx.x * blockDim.x + threadIdx.x;
  const int A = 512*512, Bc = 512*512, C = 256*512, Dn = 512*544;
  if (idx < A) {
    w2h[idx] = (_Float16)e2w[idx];
  } else if (idx < A + Bc) {
    int q = idx - A; w3h[q] = (_Float16)e3w[q];
  } else if (idx < A + Bc + C) {
    int q = idx - A - Bc; n2wh[q] = (_Float16)n2w[q];
  } else if (idx < A + Bc + C + Dn) {
    int q = idx - A - Bc - C;
    int n = q / 544, k = q % 544;
    n1wh[q] = (k < 520) ? (_Float16)n1w[n*520 + k] : (_Float16)0.0f;
  }
}

__global__ void prep_stfeat_kernel(const float* __restrict__ state,
                                   const float* __restrict__ lw,
                                   const float* __restrict__ lb,
                                   float* __restrict__ xfeat) {
  const int b = blockIdx.x, c = threadIdx.x;  // 512
  const float* s = state + b*4;
  const float* wr = lw + c*4;
  float hv = wr[0]*s[0] + wr[1]*s[1] + wr[2]*s[2] + wr[3]*s[3] + lb[c];
  xfeat[b*1024 + c] = fmaxf(hv, 0.0f);
}

// ----------------------------------------------------- edge (fused MLP) ----
// One WG = 128 edge rows = 2 (b,i) groups x 64 j. 512 threads = 8 waves;
// wave w owns output cols [w*64, w*64+64). H1/H2 live in one 128 KB LDS
// buffer (rows 128 x 512 f16), XOR-swizzled:
//   byte(row, k_elem) = (row*1024 + k_elem*2) ^ ((row&7)<<4)
// Weights stream from L2 directly into B-fragments (no sharing across
// waves -> no LDS staging, no per-k barriers). Only 3 barriers total.

__global__ __launch_bounds__(512, 2) void edge_fused(
    const _Float16* __restrict__ u16, const _Float16* __restrict__ v16,
    const _Float16* __restrict__ w2h, const _Float16* __restrict__ w3h,
    const float* __restrict__ e2b, const float* __restrict__ e3b,
    const float* __restrict__ maskp, const float* __restrict__ cntp,
    float* __restrict__ agg) {
  __shared__ __align__(16) char lds[131072];
  __shared__ float em_s[64];

  const int t = threadIdx.x;
  const int bi0 = blockIdx.x * 2;
  const int b = bi0 >> 6;
  const int w = t >> 6, l = t & 63, lr = l & 15, lg = l >> 4;
  const int wcol = w * 64;

  if (t < 64) em_s[t] = maskp[(size_t)b*64 + t];

  // ---- build H1 = relu(u_i + v_j), rows 0-63 = group0, 64-127 = group1
  {
    const int tr = t >> 3;        // j  (0..63)
    const int kc = t & 7;         // 64-elem k block
    const _Float16* vrow = v16 + ((size_t)(b*64 + tr))*NH + kc*64;
    const _Float16* u0p  = u16 + (size_t)bi0*NH + kc*64;
    const _Float16* u1p  = u16 + (size_t)(bi0 + 1)*NH + kc*64;
    #pragma unroll
    for (int e8 = 0; e8 < 8; ++e8) {
      f16x8 vv = *(const f16x8*)(vrow + e8*8);
      f16x8 u0 = *(const f16x8*)(u0p + e8*8);
      f16x8 u1 = *(const f16x8*)(u1p + e8*8);
      f16x8 h0, h1;
      #pragma unroll
      for (int e = 0; e < 8; ++e) {
        _Float16 x0 = u0[e] + vv[e];
        _Float16 x1 = u1[e] + vv[e];
        h0[e] = x0 > (_Float16)0 ? x0 : (_Float16)0;
        h1[e] = x1 > (_Float16)0 ? x1 : (_Float16)0;
      }
      const int k16 = (kc*8 + e8)*16;   // byte offset of 8-elem block
      *(f16x8*)(lds + ((tr*1024 + k16) ^ ((tr & 7) << 4))) = h0;
      *(f16x8*)(lds + (((64 + tr)*1024 + k16) ^ ((tr & 7) << 4))) = h1;
    }
  }
  __syncthreads();

  f32x4 acc[8][4];

  // ---- layer 2: acc = H1 @ W2^T + b2 (each wave its own 64 cols)
  {
    #pragma unroll
    for (int nt = 0; nt < 4; ++nt) {
      float bz = e2b[wcol + nt*16 + lr];
      #pragma unroll
      for (int mt = 0; mt < 8; ++mt) {
        acc[mt][nt][0] = bz; acc[mt][nt][1] = bz;
        acc[mt][nt][2] = bz; acc[mt][nt][3] = bz;
      }
    }
    const _Float16* bbase = w2h + (size_t)(wcol + lr)*NH + lg*8;
    f16x8 bfp[4];
    #pragma unroll
    for (int nt = 0; nt < 4; ++nt)
      bfp[nt] = *(const f16x8*)(bbase + nt*16*NH);
    for (int kk = 0; kk < 16; ++kk) {
      f16x8 bf[4];
      #pragma unroll
      for (int nt = 0; nt < 4; ++nt) bf[nt] = bfp[nt];
      if (kk < 15) {
        #pragma unroll
        for (int nt = 0; nt < 4; ++nt)
          bfp[nt] = *(const f16x8*)(bbase + nt*16*NH + (kk+1)*32);
      }
      const int k16 = (kk*4 + lg)*16;
      #pragma unroll
      for (int mt = 0; mt < 8; ++mt) {
        int row = mt*16 + lr;
        f16x8 af = *(const f16x8*)(lds + ((row*1024 + k16) ^ ((row & 7) << 4)));
        #pragma unroll
        for (int nt = 0; nt < 4; ++nt)
          acc[mt][nt] = __builtin_amdgcn_mfma_f32_16x16x32_f16(af, bf[nt], acc[mt][nt], 0, 0, 0);
      }
    }
  }
  __syncthreads();   // everyone done READING H1

  // ---- H2 = relu(acc) overwrites the same LDS buffer
  #pragma unroll
  for (int mt = 0; mt < 8; ++mt)
    #pragma unroll
    for (int nt = 0; nt < 4; ++nt)
      #pragma unroll
      for (int r = 0; r < 4; ++r) {
        int row = mt*16 + lg*4 + r;
        int cc = wcol + nt*16 + lr;
        *(_Float16*)(lds + ((row*1024 + cc*2) ^ ((row & 7) << 4))) =
            (_Float16)fmaxf(acc[mt][nt][r], 0.0f);
      }
  __syncthreads();   // H2 complete

  // ---- layer 3: acc = H2 @ W3^T + b3
  {
    #pragma unroll
    for (int nt = 0; nt < 4; ++nt) {
      float bz = e3b[wcol + nt*16 + lr];
      #pragma unroll
      for (int mt = 0; mt < 8; ++mt) {
        acc[mt][nt][0] = bz; acc[mt][nt][1] = bz;
        acc[mt][nt][2] = bz; acc[mt][nt][3] = bz;
      }
    }
    const _Float16* bbase = w3h + (size_t)(wcol + lr)*NH + lg*8;
    f16x8 bfp[4];
    #pragma unroll
    for (int nt = 0; nt < 4; ++nt)
      bfp[nt] = *(const f16x8*)(bbase + nt*16*NH);
    for (int kk = 0; kk < 16; ++kk) {
      f16x8 bf[4];
      #pragma unroll
      for (int nt = 0; nt < 4; ++nt) bf[nt] = bfp[nt];
      if (kk < 15) {
        #pragma unroll
        for (int nt = 0; nt < 4; ++nt)
          bfp[nt] = *(const f16x8*)(bbase + nt*16*NH + (kk+1)*32);
      }
      const int k16 = (kk*4 + lg)*16;
      #pragma unroll
      for (int mt = 0; mt < 8; ++mt) {
        int row = mt*16 + lr;
        f16x8 af = *(const f16x8*)(lds + ((row*1024 + k16) ^ ((row & 7) << 4)));
        #pragma unroll
        for (int nt = 0; nt < 4; ++nt)
          acc[mt][nt] = __builtin_amdgcn_mfma_f32_16x16x32_f16(af, bf[nt], acc[mt][nt], 0, 0, 0);
      }
    }
  }

  // ---- relu + mask-weighted sum over j; rows 0-63 -> bi0, 64-127 -> bi0+1
  float csum[2][4] = {{0.f,0.f,0.f,0.f},{0.f,0.f,0.f,0.f}};
  #pragma unroll
  for (int mt = 0; mt < 8; ++mt) {
    const int g = mt >> 2;
    float em0 = em_s[(mt&3)*16 + lg*4 + 0];
    float em1 = em_s[(mt&3)*16 + lg*4 + 1];
    float em2 = em_s[(mt&3)*16 + lg*4 + 2];
    float em3 = em_s[(mt&3)*16 + lg*4 + 3];
    #pragma unroll
    for (int nt = 0; nt < 4; ++nt) {
      csum[g][nt] += em0 * fmaxf(acc[mt][nt][0], 0.f)
                   + em1 * fmaxf(acc[mt][nt][1], 0.f)
                   + em2 * fmaxf(acc[mt][nt][2], 0.f)
                   + em3 * fmaxf(acc[mt][nt][3], 0.f);
    }
  }
  #pragma unroll
  for (int g = 0; g < 2; ++g)
    #pragma unroll
    for (int nt = 0; nt < 4; ++nt) {
      csum[g][nt] += __shfl_xor(csum[g][nt], 16);
      csum[g][nt] += __shfl_xor(csum[g][nt], 32);
    }
  float cnt = cntp[b];
  if (lg == 0) {
    #pragma unroll
    for (int g = 0; g < 2; ++g) {
      int big = bi0 + g;
      float sc = em_s[big & 63] / cnt;
      #pragma unroll
      for (int nt = 0; nt < 4; ++nt)
        agg[(size_t)big*NH + wcol + nt*16 + lr] = csum[g][nt] * sc;
    }
  }
}

__global__ __launch_bounds__(256) void ln_kernel(
    const float* __restrict__ agg, const float* __restrict__ lng,
    const float* __restrict__ lnb, _Float16* __restrict__ nodein) {
  const int w = threadIdx.x >> 6, l = threadIdx.x & 63;
  const int row = blockIdx.x*4 + w;
  const float* ar = agg + (size_t)row*NH + l*8;
  float4 a0 = *(const float4*)ar;
  float4 a1 = *(const float4*)(ar + 4);
  float s1 = a0.x + a0.y + a0.z + a0.w + a1.x + a1.y + a1.z + a1.w;
  float s2 = a0.x*a0.x + a0.y*a0.y + a0.z*a0.z + a0.w*a0.w
           + a1.x*a1.x + a1.y*a1.y + a1.z*a1.z + a1.w*a1.w;
  #pragma unroll
  for (int off = 1; off < 64; off <<= 1) {
    s1 += __shfl_xor(s1, off);
    s2 += __shfl_xor(s2, off);
  }
  float mean = s1 * (1.0f/512.0f);
  float rstd = rsqrtf(s2 * (1.0f/512.0f) - mean*mean + 1e-5f);
  float4 g0 = *(const float4*)(lng + l*8);
  float4 g1 = *(const float4*)(lng + l*8 + 4);
  float4 b0 = *(const float4*)(lnb + l*8);
  float4 b1 = *(const float4*)(lnb + l*8 + 4);
  f16x4 o0, o1;
  o0[0] = (_Float16)((a0.x - mean) * rstd * g0.x + b0.x);
  o0[1] = (_Float16)((a0.y - mean) * rstd * g0.y + b0.y);
  o0[2] = (_Float16)((a0.z - mean) * rstd * g0.z + b0.z);
  o0[3] = (_Float16)((a0.w - mean) * rstd * g0.w + b0.w);
  o1[0] = (_Float16)((a1.x - mean) * rstd * g1.x + b1.x);
  o1[1] = (_Float16)((a1.y - mean) * rstd * g1.y + b1.y);
  o1[2] = (_Float16)((a1.z - mean) * rstd * g1.z + b1.z);
  o1[3] = (_Float16)((a1.w - mean) * rstd * g1.w + b1.w);
  _Float16* nr = nodein + (size_t)row*NKP + 4 + l*8;
  *(f16x4*)nr = o0;
  *(f16x4*)(nr + 4) = o1;
}

// ---------------------------------------------------------------- node ----

template <int RELU16>
__global__ __launch_bounds__(256) void node_gemm(
    const _Float16* __restrict__ A, const _Float16* __restrict__ Bw,
    const float* __restrict__ bias, void* __restrict__ outp,
    int Ka, int ldo) {
  const int t = threadIdx.x;
  const int w = t >> 6, l = t & 63, lr = l & 15, lg = l >> 4;
  const int m0 = blockIdx.x * 64;
  const int col = blockIdx.y * 64 + w*16 + lr;
  f32x4 acc[4];
  float bz = bias[col];
  #pragma unroll
  for (int mt = 0; mt < 4; ++mt) {
    acc[mt][0] = bz; acc[mt][1] = bz; acc[mt][2] = bz; acc[mt][3] = bz;
  }
  const _Float16* bptr = Bw + (size_t)col*Ka + lg*8;
  const _Float16* aptr = A + (size_t)(m0 + lr)*Ka + lg*8;
  const int nkk = Ka >> 5;
  for (int kk = 0; kk < nkk; ++kk) {
    f16x8 bf = *(const f16x8*)(bptr + kk*32);
    #pragma unroll
    for (int mt = 0; mt < 4; ++mt) {
      f16x8 af = *(const f16x8*)(aptr + ((size_t)mt*16)*Ka + kk*32);
      acc[mt] = __builtin_amdgcn_mfma_f32_16x16x32_f16(af, bf, acc[mt], 0, 0, 0);
    }
  }
  #pragma unroll
  for (int mt = 0; mt < 4; ++mt)
    #pragma unroll
    for (int r = 0; r < 4; ++r) {
      int row = m0 + mt*16 + lg*4 + r;
      float vv = acc[mt][r];
      if (RELU16)
        ((_Float16*)outp)[(size_t)row*ldo + col] = (_Float16)fmaxf(vv, 0.f);
      else
        ((float*)outp)[(size_t)row*ldo + col] = vv;
    }
}

// ----------------------------------------------------------- pool/heads ----

__global__ __launch_bounds__(256) void pool_kernel(
    const float* __restrict__ nodeout, const float* __restrict__ maskp,
    const float* __restrict__ cntp, float* __restrict__ xfeat) {
  const int b = blockIdx.x;
  const int c = threadIdx.x;  // 256
  float sum = 0.f, mx = -1e9f;
  for (int i = 0; i < 64; ++i) {
    float m = maskp[b*64 + i];
    float v = nodeout[((size_t)(b*64 + i))*256 + c];
    sum += m * v;
    mx = fmaxf(mx, (m != 0.f) ? v : -1e9f);
  }
  xfeat[b*1024 + 512 + c] = sum / cntp[b];
  xfeat[b*1024 + 768 + c] = mx;
}

// heads stage 1: partial dots over a 256-wide K slice.
__global__ __launch_bounds__(256) void heads_g1(
    const float* __restrict__ xfeat,
    const float* __restrict__ mu1w, const float* __restrict__ s1w,
    float* __restrict__ part) {
  __shared__ __align__(16) float xs[256];
  const int b = blockIdx.x, h = blockIdx.y, ks = blockIdx.z;
  const int t = threadIdx.x;
  xs[t] = xfeat[b*1024 + ks*256 + t];
  __syncthreads();
  const float* wr = (h ? s1w : mu1w) + (size_t)t*1024 + ks*256;
  float a = 0.f;
  #pragma unroll 8
  for (int k = 0; k < 256; k += 4) {
    float4 ww = *(const float4*)(wr + k);
    float4 xx = *(const float4*)(xs + k);
    a += ww.x*xx.x + ww.y*xx.y + ww.z*xx.z + ww.w*xx.w;
  }
  part[(((size_t)(b*2 + h))*256 + t)*4 + ks] = a;
}

// heads stage 2+3.
__global__ __launch_bounds__(256) void heads_g23(
    const float* __restrict__ part,
    const float* __restrict__ mu1b, const float* __restrict__ s1b,
    const float* __restrict__ mu2w, const float* __restrict__ mu2b,
    const float* __restrict__ s2w, const float* __restrict__ s2b,
    const float* __restrict__ mu3w, const float* __restrict__ mu3b,
    const float* __restrict__ s3w, const float* __restrict__ s3b,
    float* __restrict__ outp) {
  __shared__ __align__(16) float h1s[256];
  __shared__ __align__(16) float h2s[128];
  const int b = blockIdx.x, h = blockIdx.y;
  const int t = threadIdx.x;
  {
    float4 pp = *(const float4*)(part + (((size_t)(b*2 + h))*256 + t)*4);
    float a = pp.x + pp.y + pp.z + pp.w + (h ? s1b : mu1b)[t];
    h1s[t] = fmaxf(a, 0.f);
  }
  __syncthreads();
  {
    const int o = t >> 1, half = t & 1;
    const float* wr = (h ? s2w : mu2w) + (size_t)o*256 + half*128;
    const float* hp = h1s + half*128;
    float a = 0.f;
    #pragma unroll 8
    for (int k = 0; k < 128; k += 4) {
      float4 ww = *(const float4*)(wr + k);
      float4 hh = *(const float4*)(hp + k);
      a += ww.x*hh.x + ww.y*hh.y + ww.z*hh.z + ww.w*hh.w;
    }
    a += __shfl_xor(a, 1);
    if (half == 0) h2s[o] = fmaxf(a + (h ? s2b : mu2b)[o], 0.f);
  }
  __syncthreads();
  if (t < 64) {
    const int o = t >> 5, lane = t & 31;
    const float* wr = (h ? s3w : mu3w) + o*128 + lane*4;
    const float* hp = h2s + lane*4;
    float4 ww = *(const float4*)wr;
    float4 hh = *(const float4*)hp;
    float a = ww.x*hh.x + ww.y*hh.y + ww.z*hh.z + ww.w*hh.w;
    #pragma unroll
    for (int off = 1; off < 32; off <<= 1) a += __shfl_xor(a, off);
    if (lane == 0) {
      a += (h ? s3b : mu3b)[o];
      if (h == 0) {
        outp[b*2 + o] = a;
      } else {
        float spv = (a > 0.f) ? (a + log1pf(expf(-a))) : log1pf(expf(a));
        outp[64 + b*2 + o] = fminf(fmaxf(spv + 0.001f, 0.1f), 2.0f);
      }
    }
  }
}

// --------------------------------------------------------------- launch ----

extern "C" void kernel_launch(void* const* d_in, const int* in_sizes, int n_in,
                              void* d_out, int out_size, void* d_ws, size_t ws_size,
                              hipStream_t stream) {
  const float* state  = (const float*)d_in[0];
  const float* obs    = (const float*)d_in[1];
  const float* layerw = (const float*)d_in[2];
  const float* layerb = (const float*)d_in[3];
  const float* e1w    = (const float*)d_in[4];
  const float* e1b    = (const float*)d_in[5];
  const float* e2w    = (const float*)d_in[6];
  const float* e2b    = (const float*)d_in[7];
  const float* e3w    = (const float*)d_in[8];
  const float* e3b    = (const float*)d_in[9];
  const float* lng    = (const float*)d_in[10];
  const float* lnb    = (const float*)d_in[11];
  const float* n1w    = (const float*)d_in[12];
  const float* n1b    = (const float*)d_in[13];
  const float* n2w    = (const float*)d_in[14];
  const float* n2b    = (const float*)d_in[15];
  const float* mu1w   = (const float*)d_in[16];
  const float* mu1b   = (const float*)d_in[17];
  const float* mu2w   = (const float*)d_in[18];
  const float* mu2b   = (const float*)d_in[19];
  const float* mu3w   = (const float*)d_in[20];
  const float* mu3b   = (const float*)d_in[21];
  const float* s1w    = (const float*)d_in[22];
  const float* s1b    = (const float*)d_in[23];
  const float* s2w    = (const float*)d_in[24];
  const float* s2b    = (const float*)d_in[25];
  const float* s3w    = (const float*)d_in[26];
  const float* s3b    = (const float*)d_in[27];
  float* outp = (float*)d_out;

  char* p = (char*)d_ws;
  auto alloc = [&](size_t bytes) {
    char* r = p;
    p += (bytes + 255) & ~(size_t)255;
    return r;
  };
  float*    o       = (float*)alloc((size_t)2048*4*4);
  float*    maskp   = (float*)alloc((size_t)2048*4);
  float*    cntp    = (float*)alloc((size_t)32*4);
  _Float16* u16     = (_Float16*)alloc((size_t)2048*512*2);
  _Float16* v16     = (_Float16*)alloc((size_t)2048*512*2);
  _Float16* w2h     = (_Float16*)alloc((size_t)512*512*2);
  _Float16* w3h     = (_Float16*)alloc((size_t)512*512*2);
  _Float16* nodein  = (_Float16*)alloc((size_t)2048*544*2);
  _Float16* n1wh    = (_Float16*)alloc((size_t)512*544*2);
  _Float16* n2wh    = (_Float16*)alloc((size_t)256*512*2);
  _Float16* nodeh   = (_Float16*)alloc((size_t)2048*512*2);
  float*    nodeout = (float*)alloc((size_t)2048*256*4);
  float*    xfeat   = (float*)alloc((size_t)32*1024*4);
  float*    agg     = (float*)alloc((size_t)2048*512*4);
  float*    hpart   = (float*)alloc((size_t)32*2*256*4*4);

  prep_obs_kernel<<<32, 64, 0, stream>>>(obs, state, o, maskp, cntp, nodein);
  prep_uv16<<<2048, 512, 0, stream>>>(o, e1w, e1b, u16, v16);
  prep_w16_kernel<<<3648, 256, 0, stream>>>(e2w, e3w, n2w, n1w, w2h, w3h, n2wh, n1wh);
  prep_stfeat_kernel<<<32, 512, 0, stream>>>(state, layerw, layerb, xfeat);

  edge_fused<<<1024, 512, 0, stream>>>(u16, v16, w2h, w3h, e2b, e3b,
                                       maskp, cntp, agg);
  ln_kernel<<<512, 256, 0, stream>>>(agg, lng, lnb, nodein);

  node_gemm<1><<<dim3(32, 8), 256, 0, stream>>>(nodein, n1wh, n1b, (void*)nodeh, 544, 512);
  node_gemm<0><<<dim3(32, 4), 256, 0, stream>>>(nodeh, n2wh, n2b, (void*)nodeout, 512, 256);
  pool_kernel<<<32, 256, 0, stream>>>(nodeout, maskp, cntp, xfeat);
  heads_g1<<<dim3(32, 2, 4), 256, 0, stream>>>(xfeat, mu1w, s1w, hpart);
  heads_g23<<<dim3(32, 2), 256, 0, stream>>>(hpart, mu1b, s1b, mu2w, mu2b,
                                             s2w, s2b, mu3w, mu3b, s3w, s3b, outp);
}